// Round 1
// 470.048 us; speedup vs baseline: 1.9521x; 1.9521x over previous
//
#include <hip/hip_runtime.h>
#include <hip/hip_bf16.h>

#define DEV __device__ __forceinline__

typedef unsigned short u16;
typedef unsigned int u32;
typedef __attribute__((ext_vector_type(8))) short bf16x8;
typedef __attribute__((ext_vector_type(4))) float f32x4;

DEV float bf2f(u16 v) { u32 u = ((u32)v) << 16; return __builtin_bit_cast(float, u); }
DEV u16 f2bf(float f) {
    u32 u = __builtin_bit_cast(u32, f);
    u32 r = (u + 0x7fffu + ((u >> 16) & 1u)) >> 16;
    return (u16)r;
}
DEV float lo16(u32 u) { return __builtin_bit_cast(float, u << 16); }
DEV float hi16(u32 u) { return __builtin_bit_cast(float, u & 0xffff0000u); }
DEV float sigm(float x) { return 1.f / (1.f + __expf(-x)); }
// clamp that also swallows NaN (fmaxf(NaN,a)=a): keeps failure modes finite
DEV float clamp4(float v) { return fminf(fmaxf(v, -1e4f), 1e4f); }
// dtype-branching scalar load (isf: 1=fp32, 0=bf16), clamped
DEV float loadf(const void* p, size_t i, int isf) {
    return isf ? clamp4(((const float*)p)[i]) : clamp4(bf2f(((const u16*)p)[i]));
}
// dtype-branching 8-element load, clamped
DEV void load8(const void* p, size_t off, int isf, float* o) {
    if (isf) {
        const float* s = (const float*)p + off;
#pragma unroll
        for (int e = 0; e < 8; ++e) o[e] = clamp4(s[e]);
    } else {
        uint4 q = *(const uint4*)((const u16*)p + off);
        o[0] = clamp4(lo16(q.x)); o[1] = clamp4(hi16(q.x));
        o[2] = clamp4(lo16(q.y)); o[3] = clamp4(hi16(q.y));
        o[4] = clamp4(lo16(q.z)); o[5] = clamp4(hi16(q.z));
        o[6] = clamp4(lo16(q.w)); o[7] = clamp4(hi16(q.w));
    }
}
DEV uint4 pack8(const float* a) {
    uint4 q;
    q.x = (u32)f2bf(a[0]) | ((u32)f2bf(a[1]) << 16);
    q.y = (u32)f2bf(a[2]) | ((u32)f2bf(a[3]) << 16);
    q.z = (u32)f2bf(a[4]) | ((u32)f2bf(a[5]) << 16);
    q.w = (u32)f2bf(a[6]) | ((u32)f2bf(a[7]) << 16);
    return q;
}
// dtype-branching 8-element store (isf: 1=fp32, 0=bf16 packed)
DEV void store8(void* p, size_t off, int isf, const float* a) {
    if (isf) {
        float* d = (float*)p + off;
        *(float4*)(d) = (float4){a[0], a[1], a[2], a[3]};
        *(float4*)(d + 4) = (float4){a[4], a[5], a[6], a[7]};
    } else {
        *(uint4*)((u16*)p + off) = pack8(a);
    }
}

// async global->LDS, 16B per lane. LDS dest is wave-uniform base + lane*16;
// global src is per-lane. (m97 staging pattern)
DEV void gload16(const void* g, void* l) {
    __builtin_amdgcn_global_load_lds(
        (const __attribute__((address_space(1))) void*)g,
        (__attribute__((address_space(3))) void*)l, 16, 0, 0);
}

// ---------------------------------------------------------------- dtype detect
// Classify d_in[0] by bf16-exponent statistics of the low u16 of each u32.
// bf16 N(0,1): low-u16 exponent in [118,130] ~99.7%. fp32: those are mantissa
// bits -> ~5%. Writes 1 (fp32) or 0 (bf16) to *flag.
__global__ void detect_dtype(const u32* __restrict__ xw, u32* __restrict__ flag) {
    const int lane = threadIdx.x & 63;
    int cnt = 0;
    for (int k = 0; k < 32; ++k) {
        u32 e = (xw[lane + 64 * k] >> 7) & 0xff;
        cnt += (e >= 118 && e <= 130) ? 1 : 0;
    }
#pragma unroll
    for (int off = 32; off > 0; off >>= 1) cnt += __shfl_xor(cnt, off, 64);
    if (lane == 0) *flag = (cnt > 1024) ? 0u : 1u;
}

// ---------------------------------------------------------------- convert to bf16 (clamped)
__global__ __launch_bounds__(256) void cvt_bf16(const void* __restrict__ src,
                                                u16* __restrict__ dst, int n8,
                                                const u32* __restrict__ flagp) {
    const int isf = (int)*flagp;
    int i = blockIdx.x * 256 + threadIdx.x;
    if (i >= n8) return;
    size_t off = (size_t)i * 8;
    float a[8];
    load8(src, off, isf, a);
    *(uint4*)(dst + off) = pack8(a);
}

// ---------------------------------------------------------------- transpose (+convert+clamp)
// src [R,C] (bf16 or fp32) -> dst [C,R] bf16. Grid (C/32, R/32), block 256.
__global__ __launch_bounds__(256) void tr_any(const void* __restrict__ src,
                                              u16* __restrict__ dst,
                                              int R, int C,
                                              const u32* __restrict__ flagp) {
    const int isf = (int)*flagp;
    __shared__ __align__(16) u16 t[32][33];
    int tx = threadIdx.x & 31, ty = threadIdx.x >> 5;
    int c0 = blockIdx.x * 32, r0 = blockIdx.y * 32;
#pragma unroll
    for (int i = 0; i < 32; i += 8)
        t[ty + i][tx] = f2bf(loadf(src, (size_t)(r0 + ty + i) * C + (c0 + tx), isf));
    __syncthreads();
#pragma unroll
    for (int i = 0; i < 32; i += 8)
        dst[(size_t)(c0 + ty + i) * R + (r0 + tx)] = t[tx][ty + i];
}

// ---------------------------------------------------------------- GEMM
// C[M,N] = Acat[M,K] * Bt[N,K]^T + bias, bf16 in (ws buffers), fp32 acc, bf16 out.
// m97 structure: global_load_lds width=16, 128x128 tile, BK=32, 4 waves 2x2,
// single LDS buffer, 2 barriers per K-step.
// B rows are PERMUTED at stage time (pre-swizzled global source, LDS linear):
//   LDS slot s holds Bt row perm(s) = (s & ~63) + (s&15)*4 + ((s>>4)&3)
// so fragment t / lane (lane&15) owns output column wn*64 + 4*(lane&15) + t.
// Epilogue then packs 4 consecutive columns per lane -> one dwordx2 store,
// each 16-lane group writes a full 128B line (kills partial-line write amp).
__global__ __launch_bounds__(256) void gemm_bt(
    const u16* __restrict__ A0, const u16* __restrict__ A1, int K0,
    const u16* __restrict__ Bt, const void* __restrict__ bias,
    const u32* __restrict__ flagp,
    u16* __restrict__ Cout, int M, int N, int K) {
    const int isf = (int)*flagp;
    __shared__ __align__(16) u16 As[128 * 32];   // [m][k] linear
    __shared__ __align__(16) u16 Bs[128 * 32];   // [slot][k] linear (rows permuted at src)
    const int tid = threadIdx.x;
    const int wave = tid >> 6, lane = tid & 63;
    const int wm = wave >> 1, wn = wave & 1;

    // XCD-aware chunked swizzle (m157/m192): dispatch d -> XCD d%8; give each
    // XCD a contiguous logical chunk. Both grids here have nwg % 8 == 0.
    int bx = blockIdx.x, by = blockIdx.y;
    {
        const int gx = gridDim.x;
        const int nwg = gx * gridDim.y;
        if ((nwg & 7) == 0) {
            int lid = by * gx + bx;
            int swz = (lid & 7) * (nwg >> 3) + (lid >> 3);
            bx = swz % gx; by = swz / gx;
        }
    }
    const int m0 = by * 128, n0 = bx * 128;

    f32x4 acc[4][4];
#pragma unroll
    for (int i = 0; i < 4; ++i)
#pragma unroll
        for (int j = 0; j < 4; ++j) acc[i][j] = (f32x4){0.f, 0.f, 0.f, 0.f};

    const int mrow = lane & 15;        // MFMA m/n index
    const int kfr = (lane >> 4) * 8;   // MFMA k offset (elements)

    // staging geometry: call i covers v = tid + 256*i; row v>>2, kq (v&3)*8;
    // LDS bytes land at v*16 (linear).
    const int sr = tid >> 2;                 // 0..63 (call 0); +64 for call 1
    const int skq = (tid & 3) * 8;
    const int pb0 = (sr & ~63) + (sr & 15) * 4 + ((sr >> 4) & 3);
    const int sr1 = sr + 64;
    const int pb1 = (sr1 & ~63) + (sr1 & 15) * 4 + ((sr1 >> 4) & 3);
    u16* AsW0 = As + wave * 512;             // wave base (u16): wave*1024B
    u16* AsW1 = As + 2048 + wave * 512;      // +4096B for call 1
    u16* BsW0 = Bs + wave * 512;
    u16* BsW1 = Bs + 2048 + wave * 512;

    for (int k0 = 0; k0 < K; k0 += 32) {
        const u16* Ab; int lda, kk;
        if (k0 < K0) { Ab = A0; lda = K0; kk = k0; }
        else         { Ab = A1; lda = K - K0; kk = k0 - K0; }
        gload16(Ab + (size_t)(m0 + sr) * lda + kk + skq, AsW0);
        gload16(Ab + (size_t)(m0 + sr1) * lda + kk + skq, AsW1);
        gload16(Bt + (size_t)(n0 + pb0) * K + k0 + skq, BsW0);
        gload16(Bt + (size_t)(n0 + pb1) * K + k0 + skq, BsW1);
        __syncthreads();   // vmcnt(0) drain + barrier: LDS tile ready
        bf16x8 af[4], bfr[4];
#pragma unroll
        for (int t = 0; t < 4; ++t)
            af[t] = *(const bf16x8*)&As[(wm * 64 + t * 16 + mrow) * 32 + kfr];
#pragma unroll
        for (int t = 0; t < 4; ++t)
            bfr[t] = *(const bf16x8*)&Bs[(wn * 64 + t * 16 + mrow) * 32 + kfr];
#pragma unroll
        for (int mt = 0; mt < 4; ++mt)
#pragma unroll
            for (int nt = 0; nt < 4; ++nt)
                acc[mt][nt] = __builtin_amdgcn_mfma_f32_16x16x32_bf16(
                    af[mt], bfr[nt], acc[mt][nt], 0, 0, 0);
        __syncthreads();   // protect LDS from next iteration's stage
    }

    // epilogue: lane owns cols cbase..cbase+3 (consecutive) for 16 rows.
    const int cbase = n0 + wn * 64 + mrow * 4;
    float bv[4];
#pragma unroll
    for (int t = 0; t < 4; ++t) bv[t] = loadf(bias, cbase + t, isf);
#pragma unroll
    for (int mt = 0; mt < 4; ++mt) {
        int row0 = m0 + wm * 64 + mt * 16 + (lane >> 4) * 4;
#pragma unroll
        for (int r = 0; r < 4; ++r) {
            uint2 p;
            p.x = (u32)f2bf(acc[mt][0][r] + bv[0]) |
                  ((u32)f2bf(acc[mt][1][r] + bv[1]) << 16);
            p.y = (u32)f2bf(acc[mt][2][r] + bv[2]) |
                  ((u32)f2bf(acc[mt][3][r] + bv[3]) << 16);
            *(uint2*)(Cout + (size_t)(row0 + r) * N + cbase) = p;
        }
    }
}

// ---------------------------------------------------------------- attn + x_mod
// One wave per row: cos(im,hx) -> fac = 1+sigmoid -> xmod = x*fac. bf16 ws bufs.
__global__ __launch_bounds__(256) void attn_xmod(
    const u16* __restrict__ im, const u16* __restrict__ hx,
    const u16* __restrict__ x, u16* __restrict__ xmod) {
    const int lane = threadIdx.x & 63;
    const int row = blockIdx.x * 4 + (threadIdx.x >> 6);
    float dot = 0.f, na = 0.f, nb = 0.f;
#pragma unroll
    for (int j = 0; j < 2; ++j) {
        size_t off = (size_t)row * 1024 + lane * 8 + j * 512;
        float a[8], h[8];
        load8(im, off, 0, a);
        load8(hx, off, 0, h);
#pragma unroll
        for (int e = 0; e < 8; ++e) {
            dot += a[e] * h[e]; na += a[e] * a[e]; nb += h[e] * h[e];
        }
    }
#pragma unroll
    for (int off = 32; off > 0; off >>= 1) {
        dot += __shfl_xor(dot, off, 64);
        na += __shfl_xor(na, off, 64);
        nb += __shfl_xor(nb, off, 64);
    }
    float cs = dot / (fmaxf(sqrtf(na), 1e-6f) * fmaxf(sqrtf(nb), 1e-6f));
    float fac = 1.f + sigm(cs);
#pragma unroll
    for (int j = 0; j < 2; ++j) {
        size_t off = (size_t)row * 1024 + lane * 8 + j * 512;
        float a[8];
        load8(x, off, 0, a);
#pragma unroll
        for (int e = 0; e < 8; ++e) a[e] *= fac;
        *(uint4*)(xmod + off) = pack8(a);
    }
}

// ---------------------------------------------------------------- LN + LSTM + cosine-mod
// Outputs written in the DETECTED dtype (fp32 expected): h at [0,BH), c at [BH,2BH).
__global__ __launch_bounds__(256) void ln_lstm(
    const u16* __restrict__ gates, const void* __restrict__ cx,
    const void* __restrict__ gammas, const void* __restrict__ betas,
    const u32* __restrict__ flagp, void* __restrict__ out, int BH) {
    const int isf = (int)*flagp;
    const int lane = threadIdx.x & 63;
    const int row = blockIdx.x * 4 + (threadIdx.x >> 6);
    float v[4][16];
    float s[4] = {0.f, 0.f, 0.f, 0.f}, ss[4] = {0.f, 0.f, 0.f, 0.f};
#pragma unroll
    for (int c = 0; c < 4; ++c) {
#pragma unroll
        for (int j = 0; j < 2; ++j) {
            size_t off = (size_t)row * 4096 + c * 1024 + lane * 8 + j * 512;
            float* vp = &v[c][j * 8];
            load8(gates, off, 0, vp);
#pragma unroll
            for (int e = 0; e < 8; ++e) { s[c] += vp[e]; ss[c] += vp[e] * vp[e]; }
        }
    }
#pragma unroll
    for (int off = 32; off > 0; off >>= 1) {
#pragma unroll
        for (int c = 0; c < 4; ++c) {
            s[c] += __shfl_xor(s[c], off, 64);
            ss[c] += __shfl_xor(ss[c], off, 64);
        }
    }
    float mean[4], rstd[4];
#pragma unroll
    for (int c = 0; c < 4; ++c) {
        mean[c] = s[c] * (1.f / 1024.f);
        float var = ss[c] * (1.f / 1024.f) - mean[c] * mean[c];
        rstd[c] = rsqrtf(fmaxf(var, 0.f) + 1e-5f);
    }
#pragma unroll
    for (int c = 0; c < 4; ++c) {
#pragma unroll
        for (int j = 0; j < 2; ++j) {
            size_t off = (size_t)(c * 1024 + lane * 8 + j * 512);
            float g[8], bb[8];
            load8(gammas, off, isf, g);
            load8(betas, off, isf, bb);
            float* vp = &v[c][j * 8];
#pragma unroll
            for (int e = 0; e < 8; ++e) {
                float y = (vp[e] - mean[c]) * rstd[c] * g[e] + bb[e];
                vp[e] = (c == 2) ? tanhf(y) : sigm(y);
            }
        }
    }
    float hn[16], cn[16];
    float dot = 0.f, nh = 0.f, nc = 0.f;
#pragma unroll
    for (int j = 0; j < 2; ++j) {
        size_t off = (size_t)row * 1024 + lane * 8 + j * 512;
        float cv[8];
        load8(cx, off, isf, cv);
#pragma unroll
        for (int e = 0; e < 8; ++e) {
            int idx = j * 8 + e;
            float c_new = v[1][idx] * cv[e] + v[0][idx] * v[2][idx];
            float h_new = v[3][idx] * tanhf(c_new);
            cn[idx] = c_new; hn[idx] = h_new;
            dot += h_new * c_new; nh += h_new * h_new; nc += c_new * c_new;
        }
    }
#pragma unroll
    for (int off = 32; off > 0; off >>= 1) {
        dot += __shfl_xor(dot, off, 64);
        nh += __shfl_xor(nh, off, 64);
        nc += __shfl_xor(nc, off, 64);
    }
    float cs = dot / (fmaxf(sqrtf(nh), 1e-6f) * fmaxf(sqrtf(nc), 1e-6f));
    float fac = 1.f + sigm((cs + 1.f) * 0.5f);
#pragma unroll
    for (int j = 0; j < 2; ++j) {
        size_t off = (size_t)row * 1024 + lane * 8 + j * 512;
        float ho[8];
#pragma unroll
        for (int e = 0; e < 8; ++e) ho[e] = hn[j * 8 + e] * fac;
        store8(out, off, isf, ho);
        store8(out, (size_t)BH + off, isf, &cn[j * 8]);
    }
}

// ---------------------------------------------------------------- diagnostics
// Sentinels use clean-mantissa fp32 (low 16 bits zero) so they decode to the
// same magnitude whether the harness reads fp32 or bf16 pairs:
//   out word0 = 65536  : in_sizes / out_size mismatch
//   out word0 = 131072 : ws too small
//   out word0 = 32768  : MFMA fragment-layout self-test failed
__global__ void diag_k(u32* __restrict__ out, int ws_ok, int sizes_ok) {
    const int lane = threadIdx.x & 63;
    int mrow = lane & 15, quad = lane >> 4;
    bf16x8 af, bfr;
#pragma unroll
    for (int j = 0; j < 8; ++j) {
        int k = quad * 8 + j;
        af[j] = (short)f2bf((float)(((mrow * 7 + k * 3) % 11) - 5));
        bfr[j] = (short)f2bf((float)(((mrow * 5 + k * 2) % 13) - 6));
    }
    f32x4 cacc = (f32x4){0.f, 0.f, 0.f, 0.f};
    cacc = __builtin_amdgcn_mfma_f32_16x16x32_bf16(af, bfr, cacc, 0, 0, 0);
    int bad = 0;
#pragma unroll
    for (int r = 0; r < 4; ++r) {
        int mr = quad * 4 + r;
        float expv = 0.f;
        for (int k = 0; k < 32; ++k)
            expv += (float)(((mr * 7 + k * 3) % 11) - 5) *
                    (float)(((mrow * 5 + k * 2) % 13) - 6);
        if (fabsf(cacc[r] - expv) > 0.5f) bad = 1;
    }
    int mfma_bad = (__ballot(bad) != 0ull) ? 1 : 0;
    if (lane == 0) {
        if (!sizes_ok)     out[0] = __builtin_bit_cast(u32, 65536.f);
        else if (!ws_ok)   out[0] = __builtin_bit_cast(u32, 131072.f);
        else if (mfma_bad) out[0] = __builtin_bit_cast(u32, 32768.f);
    }
}

// ---------------------------------------------------------------- launch
extern "C" void kernel_launch(void* const* d_in, const int* in_sizes, int n_in,
                              void* d_out, int out_size, void* d_ws, size_t ws_size,
                              hipStream_t stream) {
    const void* x   = d_in[0];  // [8192,1024]
    const void* hx  = d_in[1];  // [8192,1024]
    const void* cx  = d_in[2];  // [8192,1024]
    const void* W   = d_in[3];  // [2048,4096]
    const void* b   = d_in[4];  // [4096]
    const void* Wm  = d_in[5];  // [1024,1024]
    const void* bm  = d_in[6];  // [1024]
    const void* gam = d_in[7];  // [4,1024]
    const void* bet = d_in[8];  // [4,1024]

    const int B = 8192, I = 1024, H = 1024;
    const int K2 = I + H, N2 = 4 * H;
    const size_t MiB = 1048576ull;

    // ws layout (bf16 working buffers; 114 MiB + flag):
    //   x_c   [8192,1024] @ 0      (16 MiB)
    //   hx_c  [8192,1024] @ 16     (16 MiB)
    //   Wt    [4096,2048] @ 32     (16 MiB)
    //   Wmt   [1024,1024] @ 48     (2 MiB)
    //   gates [8192,4096] @ 50     (64 MiB)
    //   flag  u32         @ 114 MiB
    // d_out as scratch: xmod(bf16) @ byte 0 (16 MiB), imb(bf16) @ byte 16 MiB
    // (out buffer is >=32 MiB under either out dtype; both dead before ln_lstm).
    char* ws = (char*)d_ws;
    u16* x_c   = (u16*)ws;
    u16* hx_c  = (u16*)(ws + 16 * MiB);
    u16* Wt    = (u16*)(ws + 32 * MiB);
    u16* Wmt   = (u16*)(ws + 48 * MiB);
    u16* gates = (u16*)(ws + 50 * MiB);
    u32* flag  = (u32*)(ws + 114 * MiB);
    u16* xmod  = (u16*)d_out;
    u16* imb   = (u16*)d_out + 8388608ull;

    const int sizes_ok =
        n_in == 9 && out_size == 16777216 &&
        in_sizes[0] == 8388608 && in_sizes[1] == 8388608 && in_sizes[2] == 8388608 &&
        in_sizes[3] == 8388608 && in_sizes[4] == 4096 && in_sizes[5] == 1048576 &&
        in_sizes[6] == 1024 && in_sizes[7] == 4096 && in_sizes[8] == 4096;
    const int ws_ok = ws_size >= 115 * MiB;

    if (sizes_ok && ws_ok) {
        detect_dtype<<<1, 64, 0, stream>>>((const u32*)x, flag);
        cvt_bf16<<<4096, 256, 0, stream>>>(x, x_c, 1048576, flag);
        cvt_bf16<<<4096, 256, 0, stream>>>(hx, hx_c, 1048576, flag);
        tr_any<<<dim3(H / 32, I / 32), 256, 0, stream>>>(Wm, Wmt, I, H, flag);
        tr_any<<<dim3(N2 / 32, K2 / 32), 256, 0, stream>>>(W, Wt, K2, N2, flag);
        // im = x @ Wm + bm
        gemm_bt<<<dim3(H / 128, B / 128), 256, 0, stream>>>(
            x_c, x_c, I, Wmt, bm, flag, imb, B, H, I);
        attn_xmod<<<dim3(B / 4), 256, 0, stream>>>(imb, hx_c, x_c, xmod);
        // gates = [xmod|hx] @ W + b
        gemm_bt<<<dim3(N2 / 128, B / 128), 256, 0, stream>>>(
            xmod, hx_c, I, Wt, b, flag, gates, B, N2, K2);
        ln_lstm<<<dim3(B / 4), 256, 0, stream>>>(gates, cx, gam, bet, flag,
                                                 d_out, B * H);
    }
    diag_k<<<1, 64, 0, stream>>>((u32*)d_out, ws_ok, sizes_ok);
}

// Round 2
// 421.858 us; speedup vs baseline: 2.1751x; 1.1142x over previous
//
#include <hip/hip_runtime.h>
#include <hip/hip_bf16.h>

#define DEV __device__ __forceinline__

typedef unsigned short u16;
typedef unsigned int u32;
typedef __attribute__((ext_vector_type(8))) short bf16x8;
typedef __attribute__((ext_vector_type(4))) float f32x4;

DEV float bf2f(u16 v) { u32 u = ((u32)v) << 16; return __builtin_bit_cast(float, u); }
DEV u16 f2bf(float f) {
    u32 u = __builtin_bit_cast(u32, f);
    u32 r = (u + 0x7fffu + ((u >> 16) & 1u)) >> 16;
    return (u16)r;
}
DEV float lo16(u32 u) { return __builtin_bit_cast(float, u << 16); }
DEV float hi16(u32 u) { return __builtin_bit_cast(float, u & 0xffff0000u); }
DEV float sigm(float x) { return 1.f / (1.f + __expf(-x)); }
// clamp that also swallows NaN (fmaxf(NaN,a)=a): keeps failure modes finite
DEV float clamp4(float v) { return fminf(fmaxf(v, -1e4f), 1e4f); }
// dtype-branching scalar load (isf: 1=fp32, 0=bf16), clamped
DEV float loadf(const void* p, size_t i, int isf) {
    return isf ? clamp4(((const float*)p)[i]) : clamp4(bf2f(((const u16*)p)[i]));
}
// dtype-branching 8-element load, clamped
DEV void load8(const void* p, size_t off, int isf, float* o) {
    if (isf) {
        const float* s = (const float*)p + off;
#pragma unroll
        for (int e = 0; e < 8; ++e) o[e] = clamp4(s[e]);
    } else {
        uint4 q = *(const uint4*)((const u16*)p + off);
        o[0] = clamp4(lo16(q.x)); o[1] = clamp4(hi16(q.x));
        o[2] = clamp4(lo16(q.y)); o[3] = clamp4(hi16(q.y));
        o[4] = clamp4(lo16(q.z)); o[5] = clamp4(hi16(q.z));
        o[6] = clamp4(lo16(q.w)); o[7] = clamp4(hi16(q.w));
    }
}
DEV uint4 pack8(const float* a) {
    uint4 q;
    q.x = (u32)f2bf(a[0]) | ((u32)f2bf(a[1]) << 16);
    q.y = (u32)f2bf(a[2]) | ((u32)f2bf(a[3]) << 16);
    q.z = (u32)f2bf(a[4]) | ((u32)f2bf(a[5]) << 16);
    q.w = (u32)f2bf(a[6]) | ((u32)f2bf(a[7]) << 16);
    return q;
}
// dtype-branching 8-element store (isf: 1=fp32, 0=bf16 packed)
DEV void store8(void* p, size_t off, int isf, const float* a) {
    if (isf) {
        float* d = (float*)p + off;
        *(float4*)(d) = (float4){a[0], a[1], a[2], a[3]};
        *(float4*)(d + 4) = (float4){a[4], a[5], a[6], a[7]};
    } else {
        *(uint4*)((u16*)p + off) = pack8(a);
    }
}

// async global->LDS, 16B per lane. LDS dest is wave-uniform base + lane*16;
// global src is per-lane. (m97/m201 staging pattern)
DEV void gload16(const void* g, void* l) {
    __builtin_amdgcn_global_load_lds(
        (const __attribute__((address_space(1))) void*)g,
        (__attribute__((address_space(3))) void*)l, 16, 0, 0);
}

// ---------------------------------------------------------------- dtype detect
__global__ void detect_dtype(const u32* __restrict__ xw, u32* __restrict__ flag) {
    const int lane = threadIdx.x & 63;
    int cnt = 0;
    for (int k = 0; k < 32; ++k) {
        u32 e = (xw[lane + 64 * k] >> 7) & 0xff;
        cnt += (e >= 118 && e <= 130) ? 1 : 0;
    }
#pragma unroll
    for (int off = 32; off > 0; off >>= 1) cnt += __shfl_xor(cnt, off, 64);
    if (lane == 0) *flag = (cnt > 1024) ? 0u : 1u;
}

// ---------------------------------------------------------------- convert to bf16 (clamped)
__global__ __launch_bounds__(256) void cvt_bf16(const void* __restrict__ src,
                                                u16* __restrict__ dst, int n8,
                                                const u32* __restrict__ flagp) {
    const int isf = (int)*flagp;
    int i = blockIdx.x * 256 + threadIdx.x;
    if (i >= n8) return;
    size_t off = (size_t)i * 8;
    float a[8];
    load8(src, off, isf, a);
    *(uint4*)(dst + off) = pack8(a);
}

// ---------------------------------------------------------------- transpose (+convert+clamp)
__global__ __launch_bounds__(256) void tr_any(const void* __restrict__ src,
                                              u16* __restrict__ dst,
                                              int R, int C,
                                              const u32* __restrict__ flagp) {
    const int isf = (int)*flagp;
    __shared__ __align__(16) u16 t[32][33];
    int tx = threadIdx.x & 31, ty = threadIdx.x >> 5;
    int c0 = blockIdx.x * 32, r0 = blockIdx.y * 32;
#pragma unroll
    for (int i = 0; i < 32; i += 8)
        t[ty + i][tx] = f2bf(loadf(src, (size_t)(r0 + ty + i) * C + (c0 + tx), isf));
    __syncthreads();
#pragma unroll
    for (int i = 0; i < 32; i += 8)
        dst[(size_t)(c0 + ty + i) * R + (r0 + tx)] = t[tx][ty + i];
}

// ---------------------------------------------------------------- GEMM 256x256 8-phase
// C[M,N] = Acat[M,K] * Bt[N,K]^T + bias. bf16 in, fp32 acc, bf16 out.
// m201 template: BM=BN=256, BK=64, 8 waves (2Mx4N), 128KiB LDS (2 dbuf),
// global_load_lds w16 staging, counted vmcnt(6) once per K-tile (never 0 in
// steady state), raw s_barrier, setprio around MFMA clusters, st_16x32 LDS
// swizzle realized as linear LDS dest + inverse-swizzled GLOBAL source +
// swizzled ds_read (both-sides rule, m104/m231).
//
// LDS logical layout per operand buffer (32KB): subtiles of 16 rows x 32 k
// (1024B), subtile index s encodes the phase quadrant in its top bit so each
// 16KB "half" is read in exactly one phase:
//   A: s = mh*16 + wm*8 + mt2*2 + kb   (m = wm*128 + mh*64 + mt2*16 + lr)
//   B: s = nh*16 + wn*4  + nt2*2 + kb  (nslot = wn*64 + nh*32 + nt2*16 + lr)
// swizzle: byte ^= ((byte>>9)&1)<<5  (within-subtile: bit9 = row bit3).
// B rows additionally permuted (perm(n) = (n&~63)|((n&15)*4+((n>>4)&3))) so
// the epilogue writes 4 consecutive cols per lane (full-line uint2 stores).
//
// Phase schedule per K-tile t (quadrants (mh,nh)):
//   P1 (0,0): read A-half0(8 b128) + B-half0(4); stage B0(t+1) -> other buf
//   P2 (0,1): read B-half1(4), reuse A;           stage A0(t+2) -> cur buf
//   P3 (1,1): read A-half1(8), reuse B1;          stage B1(t+2) -> cur buf
//   P4 (1,0): re-read B-half0(4), reuse A1;       stage A1(t+2) -> cur buf
//   each phase: reads, stage, barrier, setprio(1), 16 MFMA, setprio(0), barrier
//   P4 extra: s_waitcnt vmcnt(6) (3 halves in flight) before end barrier.
// Region lifetimes verified: cur-buf stages (P2/P3/P4) only touch halves whose
// reads completed in an earlier phase of the same tile (A0@P1, B1@P2, A1@P3);
// B0 is re-read in P4 and only restaged at t+1 P1.
__global__ __launch_bounds__(512, 2) void gemm256(
    const u16* __restrict__ A0, const u16* __restrict__ A1, int K0,
    const u16* __restrict__ Bt, const void* __restrict__ bias,
    const u32* __restrict__ flagp,
    u16* __restrict__ Cout, int M, int N, int K) {
    const int isf = (int)*flagp;
    __shared__ __align__(16) u16 lds[65536];   // A: [0,32768) u16, B: [32768,65536)
    u16* const ldsA = lds;
    u16* const ldsB = lds + 32768;
    const int tid = threadIdx.x;
    const int wave = tid >> 6, lane = tid & 63;
    const int wm = wave >> 2, wn = wave & 3;

    // XCD-aware chunked swizzle (m192): nwg % 8 == 0 for both launches.
    int bx = blockIdx.x, by = blockIdx.y;
    {
        const int gx = gridDim.x;
        const int nwg = gx * gridDim.y;
        if ((nwg & 7) == 0) {
            int lid = by * gx + bx;
            int swz = (lid & 7) * (nwg >> 3) + (lid >> 3);
            bx = swz % gx; by = swz / gx;
        }
    }
    const int m0 = by * 256, n0 = bx * 256;
    const int NT = K >> 6;

    // ---- per-thread stage-source element offsets (tile-invariant).
    // Stage call (h=half, c=call) for this (wave,lane) writes LDS physical
    // bytes p..p+15; decode which LOGICAL element lands there (inverse of the
    // read swizzle) and point the global source at it. lda == K0 for both
    // segments (asserted by launcher usage).
    size_t qA[2][2], qB[2][2];
#pragma unroll
    for (int h = 0; h < 2; ++h)
#pragma unroll
        for (int c = 0; c < 2; ++c) {
            int p = h * 16384 + c * 8192 + wave * 1024 + lane * 16;
            int lg = p ^ (((p >> 9) & 1) << 5);
            int s = lg >> 10, lr = (lg >> 6) & 15;
            int k = ((s & 1) << 5) + ((lg & 63) >> 1);
            int m = ((s >> 3) & 1) * 128 + ((s >> 4) & 1) * 64 +
                    ((s >> 1) & 3) * 16 + lr;
            qA[h][c] = (size_t)(m0 + m) * (size_t)K0 + (size_t)k;
            int ns = ((s >> 2) & 3) * 64 + ((s >> 4) & 1) * 32 +
                     ((s >> 1) & 1) * 16 + lr;
            int gn = (ns & ~63) | ((ns & 15) * 4 + ((ns >> 4) & 3));
            qB[h][c] = (size_t)(n0 + gn) * (size_t)K + (size_t)k;
        }

    // ds_read fragment addressing (swizzled)
    const int mrow = lane & 15;
    const int kfr = (lane >> 4) * 8;
    const int aSwz = (mrow * 32 + kfr) ^ ((mrow & 8) << 1);

    f32x4 acc[8][4];
#pragma unroll
    for (int i = 0; i < 8; ++i)
#pragma unroll
        for (int j = 0; j < 4; ++j) acc[i][j] = (f32x4){0.f, 0.f, 0.f, 0.f};

#define ASEG(kt, AS_, KK_) const u16* AS_; int KK_; \
    if ((kt) < K0) { AS_ = A0; KK_ = (kt); } else { AS_ = A1; KK_ = (kt) - K0; }

    // ---- prologue: stage A0(0),B1(0),A1(0),B0(0) [buf0]; A0(1),B1(1),A1(1) [buf1]
    {
        ASEG(0, As0, kk0);
        gload16(As0 + qA[0][0] + kk0, ldsA + wave * 512);
        gload16(As0 + qA[0][1] + kk0, ldsA + 4096 + wave * 512);
        gload16(Bt + qB[1][0], ldsB + 8192 + wave * 512);
        gload16(Bt + qB[1][1], ldsB + 8192 + 4096 + wave * 512);
        gload16(As0 + qA[1][0] + kk0, ldsA + 8192 + wave * 512);
        gload16(As0 + qA[1][1] + kk0, ldsA + 8192 + 4096 + wave * 512);
        gload16(Bt + qB[0][0], ldsB + wave * 512);
        gload16(Bt + qB[0][1], ldsB + 4096 + wave * 512);
        if (NT > 1) {
            ASEG(64, As1, kk1);
            gload16(As1 + qA[0][0] + kk1, ldsA + 16384 + wave * 512);
            gload16(As1 + qA[0][1] + kk1, ldsA + 16384 + 4096 + wave * 512);
            gload16(Bt + qB[1][0] + 64, ldsB + 16384 + 8192 + wave * 512);
            gload16(Bt + qB[1][1] + 64, ldsB + 16384 + 8192 + 4096 + wave * 512);
            gload16(As1 + qA[1][0] + kk1, ldsA + 16384 + 8192 + wave * 512);
            gload16(As1 + qA[1][1] + kk1, ldsA + 16384 + 8192 + 4096 + wave * 512);
            asm volatile("s_waitcnt vmcnt(6)" ::: "memory");   // tile 0 landed
        } else {
            asm volatile("s_waitcnt vmcnt(0)" ::: "memory");
        }
        __builtin_amdgcn_s_barrier();
    }

    for (int t = 0; t < NT; ++t) {
        const int bufb = (t & 1) << 14;       // cur buffer base (u16)
        const int obufb = bufb ^ 16384;       // other buffer
        const int k0 = t << 6;
        bf16x8 af[4][2], bfA[2][2], bfB[2][2];

        // ---- P1: quadrant (0,0); stage B0(t+1) -> other buf
        {
            const u16* ab = &ldsA[bufb + (wm * 8) * 512];
#pragma unroll
            for (int mt2 = 0; mt2 < 4; ++mt2)
#pragma unroll
                for (int ks = 0; ks < 2; ++ks)
                    af[mt2][ks] = *(const bf16x8*)&ab[(mt2 * 2 + ks) * 512 + aSwz];
            const u16* bb = &ldsB[bufb + (wn * 4) * 512];
#pragma unroll
            for (int nt2 = 0; nt2 < 2; ++nt2)
#pragma unroll
                for (int ks = 0; ks < 2; ++ks)
                    bfA[nt2][ks] = *(const bf16x8*)&bb[(nt2 * 2 + ks) * 512 + aSwz];
        }
        if (t + 1 < NT) {
            gload16(Bt + qB[0][0] + (k0 + 64), ldsB + obufb + wave * 512);
            gload16(Bt + qB[0][1] + (k0 + 64), ldsB + obufb + 4096 + wave * 512);
        }
        __builtin_amdgcn_s_barrier();
        __builtin_amdgcn_s_setprio(1);
#pragma unroll
        for (int mt2 = 0; mt2 < 4; ++mt2)
#pragma unroll
            for (int nt2 = 0; nt2 < 2; ++nt2)
#pragma unroll
                for (int ks = 0; ks < 2; ++ks)
                    acc[mt2][nt2] = __builtin_amdgcn_mfma_f32_16x16x32_bf16(
                        af[mt2][ks], bfA[nt2][ks], acc[mt2][nt2], 0, 0, 0);
        __builtin_amdgcn_s_setprio(0);
        __builtin_amdgcn_s_barrier();

        // ---- P2: (0,1); stage A0(t+2) -> cur buf
        {
            const u16* bb = &ldsB[bufb + (16 + wn * 4) * 512];
#pragma unroll
            for (int nt2 = 0; nt2 < 2; ++nt2)
#pragma unroll
                for (int ks = 0; ks < 2; ++ks)
                    bfB[nt2][ks] = *(const bf16x8*)&bb[(nt2 * 2 + ks) * 512 + aSwz];
        }
        if (t + 2 < NT) {
            ASEG(k0 + 128, As2, kk2);
            gload16(As2 + qA[0][0] + kk2, ldsA + bufb + wave * 512);
            gload16(As2 + qA[0][1] + kk2, ldsA + bufb + 4096 + wave * 512);
        }
        __builtin_amdgcn_s_barrier();
        __builtin_amdgcn_s_setprio(1);
#pragma unroll
        for (int mt2 = 0; mt2 < 4; ++mt2)
#pragma unroll
            for (int nt2 = 0; nt2 < 2; ++nt2)
#pragma unroll
                for (int ks = 0; ks < 2; ++ks)
                    acc[mt2][2 + nt2] = __builtin_amdgcn_mfma_f32_16x16x32_bf16(
                        af[mt2][ks], bfB[nt2][ks], acc[mt2][2 + nt2], 0, 0, 0);
        __builtin_amdgcn_s_setprio(0);
        __builtin_amdgcn_s_barrier();

        // ---- P3: (1,1); stage B1(t+2) -> cur buf
        {
            const u16* ab = &ldsA[bufb + (16 + wm * 8) * 512];
#pragma unroll
            for (int mt2 = 0; mt2 < 4; ++mt2)
#pragma unroll
                for (int ks = 0; ks < 2; ++ks)
                    af[mt2][ks] = *(const bf16x8*)&ab[(mt2 * 2 + ks) * 512 + aSwz];
        }
        if (t + 2 < NT) {
            gload16(Bt + qB[1][0] + (k0 + 128), ldsB + bufb + 8192 + wave * 512);
            gload16(Bt + qB[1][1] + (k0 + 128), ldsB + bufb + 8192 + 4096 + wave * 512);
        }
        __builtin_amdgcn_s_barrier();
        __builtin_amdgcn_s_setprio(1);
#pragma unroll
        for (int mt2 = 0; mt2 < 4; ++mt2)
#pragma unroll
            for (int nt2 = 0; nt2 < 2; ++nt2)
#pragma unroll
                for (int ks = 0; ks < 2; ++ks)
                    acc[4 + mt2][2 + nt2] = __builtin_amdgcn_mfma_f32_16x16x32_bf16(
                        af[mt2][ks], bfB[nt2][ks], acc[4 + mt2][2 + nt2], 0, 0, 0);
        __builtin_amdgcn_s_setprio(0);
        __builtin_amdgcn_s_barrier();

        // ---- P4: (1,0); stage A1(t+2) -> cur buf; counted vmcnt
        {
            const u16* bb = &ldsB[bufb + (wn * 4) * 512];
#pragma unroll
            for (int nt2 = 0; nt2 < 2; ++nt2)
#pragma unroll
                for (int ks = 0; ks < 2; ++ks)
                    bfA[nt2][ks] = *(const bf16x8*)&bb[(nt2 * 2 + ks) * 512 + aSwz];
        }
        if (t + 2 < NT) {
            ASEG(k0 + 128, As3, kk3);
            gload16(As3 + qA[1][0] + kk3, ldsA + bufb + 8192 + wave * 512);
            gload16(As3 + qA[1][1] + kk3, ldsA + bufb + 8192 + 4096 + wave * 512);
        }
        __builtin_amdgcn_s_barrier();
        __builtin_amdgcn_s_setprio(1);
#pragma unroll
        for (int mt2 = 0; mt2 < 4; ++mt2)
#pragma unroll
            for (int nt2 = 0; nt2 < 2; ++nt2)
#pragma unroll
                for (int ks = 0; ks < 2; ++ks)
                    acc[4 + mt2][nt2] = __builtin_amdgcn_mfma_f32_16x16x32_bf16(
                        af[mt2][ks], bfA[nt2][ks], acc[4 + mt2][nt2], 0, 0, 0);
        __builtin_amdgcn_s_setprio(0);
        if (t + 2 < NT) {
            asm volatile("s_waitcnt vmcnt(6)" ::: "memory");   // 3 halves in flight
        } else {
            asm volatile("s_waitcnt vmcnt(0)" ::: "memory");   // tail drain
        }
        __builtin_amdgcn_s_barrier();
    }
#undef ASEG

    // ---- epilogue: lane owns 4 consecutive cols (B-row permutation)
    const int q = lane >> 4;
    const int cbase = n0 + wn * 64 + mrow * 4;
    float bv[4];
#pragma unroll
    for (int tt = 0; tt < 4; ++tt) bv[tt] = loadf(bias, cbase + tt, isf);
#pragma unroll
    for (int mt = 0; mt < 8; ++mt) {
        int row0 = m0 + wm * 128 + mt * 16 + q * 4;
#pragma unroll
        for (int r = 0; r < 4; ++r) {
            uint2 pk;
            pk.x = (u32)f2bf(acc[mt][0][r] + bv[0]) |
                   ((u32)f2bf(acc[mt][1][r] + bv[1]) << 16);
            pk.y = (u32)f2bf(acc[mt][2][r] + bv[2]) |
                   ((u32)f2bf(acc[mt][3][r] + bv[3]) << 16);
            *(uint2*)(Cout + (size_t)(row0 + r) * N + cbase) = pk;
        }
    }
}

// ---------------------------------------------------------------- attn + x_mod
__global__ __launch_bounds__(256) void attn_xmod(
    const u16* __restrict__ im, const u16* __restrict__ hx,
    const u16* __restrict__ x, u16* __restrict__ xmod) {
    const int lane = threadIdx.x & 63;
    const int row = blockIdx.x * 4 + (threadIdx.x >> 6);
    float dot = 0.f, na = 0.f, nb = 0.f;
#pragma unroll
    for (int j = 0; j < 2; ++j) {
        size_t off = (size_t)row * 1024 + lane * 8 + j * 512;
        float a[8], h[8];
        load8(im, off, 0, a);
        load8(hx, off, 0, h);
#pragma unroll
        for (int e = 0; e < 8; ++e) {
            dot += a[e] * h[e]; na += a[e] * a[e]; nb += h[e] * h[e];
        }
    }
#pragma unroll
    for (int off = 32; off > 0; off >>= 1) {
        dot += __shfl_xor(dot, off, 64);
        na += __shfl_xor(na, off, 64);
        nb += __shfl_xor(nb, off, 64);
    }
    float cs = dot / (fmaxf(sqrtf(na), 1e-6f) * fmaxf(sqrtf(nb), 1e-6f));
    float fac = 1.f + sigm(cs);
#pragma unroll
    for (int j = 0; j < 2; ++j) {
        size_t off = (size_t)row * 1024 + lane * 8 + j * 512;
        float a[8];
        load8(x, off, 0, a);
#pragma unroll
        for (int e = 0; e < 8; ++e) a[e] *= fac;
        *(uint4*)(xmod + off) = pack8(a);
    }
}

// ---------------------------------------------------------------- LN + LSTM + cosine-mod
__global__ __launch_bounds__(256) void ln_lstm(
    const u16* __restrict__ gates, const void* __restrict__ cx,
    const void* __restrict__ gammas, const void* __restrict__ betas,
    const u32* __restrict__ flagp, void* __restrict__ out, int BH) {
    const int isf = (int)*flagp;
    const int lane = threadIdx.x & 63;
    const int row = blockIdx.x * 4 + (threadIdx.x >> 6);
    float v[4][16];
    float s[4] = {0.f, 0.f, 0.f, 0.f}, ss[4] = {0.f, 0.f, 0.f, 0.f};
#pragma unroll
    for (int c = 0; c < 4; ++c) {
#pragma unroll
        for (int j = 0; j < 2; ++j) {
            size_t off = (size_t)row * 4096 + c * 1024 + lane * 8 + j * 512;
            float* vp = &v[c][j * 8];
            load8(gates, off, 0, vp);
#pragma unroll
            for (int e = 0; e < 8; ++e) { s[c] += vp[e]; ss[c] += vp[e] * vp[e]; }
        }
    }
#pragma unroll
    for (int off = 32; off > 0; off >>= 1) {
#pragma unroll
        for (int c = 0; c < 4; ++c) {
            s[c] += __shfl_xor(s[c], off, 64);
            ss[c] += __shfl_xor(ss[c], off, 64);
        }
    }
    float mean[4], rstd[4];
#pragma unroll
    for (int c = 0; c < 4; ++c) {
        mean[c] = s[c] * (1.f / 1024.f);
        float var = ss[c] * (1.f / 1024.f) - mean[c] * mean[c];
        rstd[c] = rsqrtf(fmaxf(var, 0.f) + 1e-5f);
    }
#pragma unroll
    for (int c = 0; c < 4; ++c) {
#pragma unroll
        for (int j = 0; j < 2; ++j) {
            size_t off = (size_t)(c * 1024 + lane * 8 + j * 512);
            float g[8], bb[8];
            load8(gammas, off, isf, g);
            load8(betas, off, isf, bb);
            float* vp = &v[c][j * 8];
#pragma unroll
            for (int e = 0; e < 8; ++e) {
                float y = (vp[e] - mean[c]) * rstd[c] * g[e] + bb[e];
                vp[e] = (c == 2) ? tanhf(y) : sigm(y);
            }
        }
    }
    float hn[16], cn[16];
    float dot = 0.f, nh = 0.f, nc = 0.f;
#pragma unroll
    for (int j = 0; j < 2; ++j) {
        size_t off = (size_t)row * 1024 + lane * 8 + j * 512;
        float cv[8];
        load8(cx, off, isf, cv);
#pragma unroll
        for (int e = 0; e < 8; ++e) {
            int idx = j * 8 + e;
            float c_new = v[1][idx] * cv[e] + v[0][idx] * v[2][idx];
            float h_new = v[3][idx] * tanhf(c_new);
            cn[idx] = c_new; hn[idx] = h_new;
            dot += h_new * c_new; nh += h_new * h_new; nc += c_new * c_new;
        }
    }
#pragma unroll
    for (int off = 32; off > 0; off >>= 1) {
        dot += __shfl_xor(dot, off, 64);
        nh += __shfl_xor(nh, off, 64);
        nc += __shfl_xor(nc, off, 64);
    }
    float cs = dot / (fmaxf(sqrtf(nh), 1e-6f) * fmaxf(sqrtf(nc), 1e-6f));
    float fac = 1.f + sigm((cs + 1.f) * 0.5f);
#pragma unroll
    for (int j = 0; j < 2; ++j) {
        size_t off = (size_t)row * 1024 + lane * 8 + j * 512;
        float ho[8];
#pragma unroll
        for (int e = 0; e < 8; ++e) ho[e] = hn[j * 8 + e] * fac;
        store8(out, off, isf, ho);
        store8(out, (size_t)BH + off, isf, &cn[j * 8]);
    }
}

// ---------------------------------------------------------------- diagnostics
__global__ void diag_k(u32* __restrict__ out, int ws_ok, int sizes_ok) {
    const int lane = threadIdx.x & 63;
    int mrow = lane & 15, quad = lane >> 4;
    bf16x8 af, bfr;
#pragma unroll
    for (int j = 0; j < 8; ++j) {
        int k = quad * 8 + j;
        af[j] = (short)f2bf((float)(((mrow * 7 + k * 3) % 11) - 5));
        bfr[j] = (short)f2bf((float)(((mrow * 5 + k * 2) % 13) - 6));
    }
    f32x4 cacc = (f32x4){0.f, 0.f, 0.f, 0.f};
    cacc = __builtin_amdgcn_mfma_f32_16x16x32_bf16(af, bfr, cacc, 0, 0, 0);
    int bad = 0;
#pragma unroll
    for (int r = 0; r < 4; ++r) {
        int mr = quad * 4 + r;
        float expv = 0.f;
        for (int k = 0; k < 32; ++k)
            expv += (float)(((mr * 7 + k * 3) % 11) - 5) *
                    (float)(((mrow * 5 + k * 2) % 13) - 6);
        if (fabsf(cacc[r] - expv) > 0.5f) bad = 1;
    }
    int mfma_bad = (__ballot(bad) != 0ull) ? 1 : 0;
    if (lane == 0) {
        if (!sizes_ok)     out[0] = __builtin_bit_cast(u32, 65536.f);
        else if (!ws_ok)   out[0] = __builtin_bit_cast(u32, 131072.f);
        else if (mfma_bad) out[0] = __builtin_bit_cast(u32, 32768.f);
    }
}

// ---------------------------------------------------------------- launch
extern "C" void kernel_launch(void* const* d_in, const int* in_sizes, int n_in,
                              void* d_out, int out_size, void* d_ws, size_t ws_size,
                              hipStream_t stream) {
    const void* x   = d_in[0];  // [8192,1024]
    const void* hx  = d_in[1];  // [8192,1024]
    const void* cx  = d_in[2];  // [8192,1024]
    const void* W   = d_in[3];  // [2048,4096]
    const void* b   = d_in[4];  // [4096]
    const void* Wm  = d_in[5];  // [1024,1024]
    const void* bm  = d_in[6];  // [1024]
    const void* gam = d_in[7];  // [4,1024]
    const void* bet = d_in[8];  // [4,1024]

    const int B = 8192, I = 1024, H = 1024;
    const int K2 = I + H, N2 = 4 * H;
    const size_t MiB = 1048576ull;

    // ws layout (bf16 working buffers; 114 MiB + flag):
    //   x_c   [8192,1024] @ 0      (16 MiB)
    //   hx_c  [8192,1024] @ 16     (16 MiB)
    //   Wt    [4096,2048] @ 32     (16 MiB)
    //   Wmt   [1024,1024] @ 48     (2 MiB)
    //   gates [8192,4096] @ 50     (64 MiB)
    //   flag  u32         @ 114 MiB
    // d_out as scratch: xmod(bf16) @ 0, imb(bf16) @ 16 MiB (dead before ln_lstm).
    char* ws = (char*)d_ws;
    u16* x_c   = (u16*)ws;
    u16* hx_c  = (u16*)(ws + 16 * MiB);
    u16* Wt    = (u16*)(ws + 32 * MiB);
    u16* Wmt   = (u16*)(ws + 48 * MiB);
    u16* gates = (u16*)(ws + 50 * MiB);
    u32* flag  = (u32*)(ws + 114 * MiB);
    u16* xmod  = (u16*)d_out;
    u16* imb   = (u16*)d_out + 8388608ull;

    const int sizes_ok =
        n_in == 9 && out_size == 16777216 &&
        in_sizes[0] == 8388608 && in_sizes[1] == 8388608 && in_sizes[2] == 8388608 &&
        in_sizes[3] == 8388608 && in_sizes[4] == 4096 && in_sizes[5] == 1048576 &&
        in_sizes[6] == 1024 && in_sizes[7] == 4096 && in_sizes[8] == 4096;
    const int ws_ok = ws_size >= 115 * MiB;

    if (sizes_ok && ws_ok) {
        detect_dtype<<<1, 64, 0, stream>>>((const u32*)x, flag);
        cvt_bf16<<<4096, 256, 0, stream>>>(x, x_c, 1048576, flag);
        cvt_bf16<<<4096, 256, 0, stream>>>(hx, hx_c, 1048576, flag);
        tr_any<<<dim3(H / 32, I / 32), 256, 0, stream>>>(Wm, Wmt, I, H, flag);
        tr_any<<<dim3(N2 / 32, K2 / 32), 256, 0, stream>>>(W, Wt, K2, N2, flag);
        // im = x @ Wm + bm   (K0 == lda == 1024; A1 unused since K == K0)
        gemm256<<<dim3(H / 256, B / 256), 512, 0, stream>>>(
            x_c, x_c, I, Wmt, bm, flag, imb, B, H, I);
        attn_xmod<<<dim3(B / 4), 256, 0, stream>>>(imb, hx_c, x_c, xmod);
        // gates = [xmod|hx] @ W + b   (both segments lda == K0 == 1024)
        gemm256<<<dim3(N2 / 256, B / 256), 512, 0, stream>>>(
            xmod, hx_c, I, Wt, b, flag, gates, B, N2, K2);
        ln_lstm<<<dim3(B / 4), 256, 0, stream>>>(gates, cx, gam, bet, flag,
                                                 d_out, B * H);
    }
    diag_k<<<1, 64, 0, stream>>>((u32*)d_out, ws_ok, sizes_ok);
}

// Round 3
// 412.144 us; speedup vs baseline: 2.2264x; 1.0236x over previous
//
#include <hip/hip_runtime.h>
#include <hip/hip_bf16.h>

#define DEV __device__ __forceinline__

typedef unsigned short u16;
typedef unsigned int u32;
typedef __attribute__((ext_vector_type(8))) short bf16x8;
typedef __attribute__((ext_vector_type(4))) float f32x4;

DEV float bf2f(u16 v) { u32 u = ((u32)v) << 16; return __builtin_bit_cast(float, u); }
DEV u16 f2bf(float f) {
    u32 u = __builtin_bit_cast(u32, f);
    u32 r = (u + 0x7fffu + ((u >> 16) & 1u)) >> 16;
    return (u16)r;
}
DEV float lo16(u32 u) { return __builtin_bit_cast(float, u << 16); }
DEV float hi16(u32 u) { return __builtin_bit_cast(float, u & 0xffff0000u); }
DEV float sigm(float x) { return 1.f / (1.f + __expf(-x)); }
// clamp that also swallows NaN (fmaxf(NaN,a)=a): keeps failure modes finite
DEV float clamp4(float v) { return fminf(fmaxf(v, -1e4f), 1e4f); }
// dtype-branching scalar load (isf: 1=fp32, 0=bf16), clamped
DEV float loadf(const void* p, size_t i, int isf) {
    return isf ? clamp4(((const float*)p)[i]) : clamp4(bf2f(((const u16*)p)[i]));
}
// dtype-branching 8-element load, clamped
DEV void load8(const void* p, size_t off, int isf, float* o) {
    if (isf) {
        const float* s = (const float*)p + off;
#pragma unroll
        for (int e = 0; e < 8; ++e) o[e] = clamp4(s[e]);
    } else {
        uint4 q = *(const uint4*)((const u16*)p + off);
        o[0] = clamp4(lo16(q.x)); o[1] = clamp4(hi16(q.x));
        o[2] = clamp4(lo16(q.y)); o[3] = clamp4(hi16(q.y));
        o[4] = clamp4(lo16(q.z)); o[5] = clamp4(hi16(q.z));
        o[6] = clamp4(lo16(q.w)); o[7] = clamp4(hi16(q.w));
    }
}
DEV uint4 pack8(const float* a) {
    uint4 q;
    q.x = (u32)f2bf(a[0]) | ((u32)f2bf(a[1]) << 16);
    q.y = (u32)f2bf(a[2]) | ((u32)f2bf(a[3]) << 16);
    q.z = (u32)f2bf(a[4]) | ((u32)f2bf(a[5]) << 16);
    q.w = (u32)f2bf(a[6]) | ((u32)f2bf(a[7]) << 16);
    return q;
}
// dtype-branching 8-element store (isf: 1=fp32, 0=bf16 packed)
DEV void store8(void* p, size_t off, int isf, const float* a) {
    if (isf) {
        float* d = (float*)p + off;
        *(float4*)(d) = (float4){a[0], a[1], a[2], a[3]};
        *(float4*)(d + 4) = (float4){a[4], a[5], a[6], a[7]};
    } else {
        *(uint4*)((u16*)p + off) = pack8(a);
    }
}

// async global->LDS, 16B per lane. LDS dest is wave-uniform base + lane*16;
// global src is per-lane. (m97/m201 staging pattern)
DEV void gload16(const void* g, void* l) {
    __builtin_amdgcn_global_load_lds(
        (const __attribute__((address_space(1))) void*)g,
        (__attribute__((address_space(3))) void*)l, 16, 0, 0);
}

// ---------------------------------------------------------------- dtype detect
__global__ void detect_dtype(const u32* __restrict__ xw, u32* __restrict__ flag) {
    const int lane = threadIdx.x & 63;
    int cnt = 0;
    for (int k = 0; k < 32; ++k) {
        u32 e = (xw[lane + 64 * k] >> 7) & 0xff;
        cnt += (e >= 118 && e <= 130) ? 1 : 0;
    }
#pragma unroll
    for (int off = 32; off > 0; off >>= 1) cnt += __shfl_xor(cnt, off, 64);
    if (lane == 0) *flag = (cnt > 1024) ? 0u : 1u;
}

// ---------------------------------------------------------------- convert to bf16 (clamped)
// Only runs when input is fp32; bf16 inputs are consumed directly (pointer
// select inside the consumers) so this becomes a no-op pass.
__global__ __launch_bounds__(256) void cvt_bf16(const void* __restrict__ src,
                                                u16* __restrict__ dst, int n8,
                                                const u32* __restrict__ flagp) {
    const int isf = (int)*flagp;
    if (!isf) return;
    int i = blockIdx.x * 256 + threadIdx.x;
    if (i >= n8) return;
    size_t off = (size_t)i * 8;
    float a[8];
    load8(src, off, isf, a);
    *(uint4*)(dst + off) = pack8(a);
}

// ---------------------------------------------------------------- transpose (+convert+clamp)
__global__ __launch_bounds__(256) void tr_any(const void* __restrict__ src,
                                              u16* __restrict__ dst,
                                              int R, int C,
                                              const u32* __restrict__ flagp) {
    const int isf = (int)*flagp;
    __shared__ __align__(16) u16 t[32][33];
    int tx = threadIdx.x & 31, ty = threadIdx.x >> 5;
    int c0 = blockIdx.x * 32, r0 = blockIdx.y * 32;
#pragma unroll
    for (int i = 0; i < 32; i += 8)
        t[ty + i][tx] = f2bf(loadf(src, (size_t)(r0 + ty + i) * C + (c0 + tx), isf));
    __syncthreads();
#pragma unroll
    for (int i = 0; i < 32; i += 8)
        dst[(size_t)(c0 + ty + i) * R + (r0 + tx)] = t[tx][ty + i];
}

// ---------------------------------------------------------------- GEMM 256x256
// C[M,N] = Acat[M,K] * Bt[N,K]^T + bias. bf16 in, fp32 acc, bf16 out.
// m201 geometry: BM=BN=256, BK=64, 8 waves (2Mx4N), 128KiB LDS (2 dbuf),
// global_load_lds w16, counted vmcnt(6), st_16x32 swizzle as linear-LDS-dest +
// inverse-swizzled global source + swizzled ds_read.
//
// Round-3 schedule: 5 barriers/tile (was 8). Per phase: [ds_reads | BAR |
// cur-buf stage | setprio(1) MFMAx16 setprio(0)]; reads are issued BEFORE the
// phase barrier so they overlap other waves' previous MFMA cluster; cur-buf
// stages are issued AFTER the barrier, which formally guarantees all waves'
// reads of the targeted half completed (half read in phase p => stage legal
// after BAR(p+1)). B-half0 fragments stay live P1->P4 (no re-read; 24 b128
// reads/tile instead of 28). Stage issue order per tile is unchanged
// (B0(t+1)@P1, A0(t+2)@P2, B1(t+2)@P3, A1(t+2)@P4) so the vmcnt(6) ledger is
// identical to round 2: at P4-wait of tile t-1 everything through B0(t) has
// landed; remaining 6 calls = A0/B1/A1(t+1). Tile-end barrier publishes all
// waves' landed stages before next tile's reads.
__global__ __launch_bounds__(512, 2) void gemm256(
    const u16* __restrict__ A0c, const void* __restrict__ A0r,
    const u16* __restrict__ A1c, const void* __restrict__ A1r, int K0,
    const u16* __restrict__ Bt, const void* __restrict__ bias,
    const u32* __restrict__ flagp,
    u16* __restrict__ Cout, int M, int N, int K) {
    const int isf = (int)*flagp;
    const u16* const A0 = isf ? A0c : (const u16*)A0r;
    const u16* const A1 = isf ? A1c : (const u16*)A1r;
    __shared__ __align__(16) u16 lds[65536];   // A: [0,32768) u16, B: [32768,65536)
    u16* const ldsA = lds;
    u16* const ldsB = lds + 32768;
    const int tid = threadIdx.x;
    const int wave = tid >> 6, lane = tid & 63;
    const int wm = wave >> 2, wn = wave & 3;

    // XCD-aware chunked swizzle (m192): nwg % 8 == 0 for both launches.
    int bx = blockIdx.x, by = blockIdx.y;
    {
        const int gx = gridDim.x;
        const int nwg = gx * gridDim.y;
        if ((nwg & 7) == 0) {
            int lid = by * gx + bx;
            int swz = (lid & 7) * (nwg >> 3) + (lid >> 3);
            bx = swz % gx; by = swz / gx;
        }
    }
    const int m0 = by * 256, n0 = bx * 256;
    const int NT = K >> 6;

    // ---- per-thread stage-source element offsets (tile-invariant).
    // Stage call (h=half, c=call) writes LDS physical bytes p..p+15; decode
    // which LOGICAL element lands there (inverse of the read swizzle) and
    // point the global source at it. lda == K0 for both A segments.
    size_t qA[2][2], qB[2][2];
#pragma unroll
    for (int h = 0; h < 2; ++h)
#pragma unroll
        for (int c = 0; c < 2; ++c) {
            int p = h * 16384 + c * 8192 + wave * 1024 + lane * 16;
            int lg = p ^ (((p >> 9) & 1) << 5);
            int s = lg >> 10, lr = (lg >> 6) & 15;
            int k = ((s & 1) << 5) + ((lg & 63) >> 1);
            int m = ((s >> 3) & 1) * 128 + ((s >> 4) & 1) * 64 +
                    ((s >> 1) & 3) * 16 + lr;
            qA[h][c] = (size_t)(m0 + m) * (size_t)K0 + (size_t)k;
            int ns = ((s >> 2) & 3) * 64 + ((s >> 4) & 1) * 32 +
                     ((s >> 1) & 1) * 16 + lr;
            int gn = (ns & ~63) | ((ns & 15) * 4 + ((ns >> 4) & 3));
            qB[h][c] = (size_t)(n0 + gn) * (size_t)K + (size_t)k;
        }

    // ds_read fragment addressing (swizzled)
    const int mrow = lane & 15;
    const int kfr = (lane >> 4) * 8;
    const int aSwz = (mrow * 32 + kfr) ^ ((mrow & 8) << 1);

    f32x4 acc[8][4];
#pragma unroll
    for (int i = 0; i < 8; ++i)
#pragma unroll
        for (int j = 0; j < 4; ++j) acc[i][j] = (f32x4){0.f, 0.f, 0.f, 0.f};

#define ASEG(kt, AS_, KK_) const u16* AS_; int KK_; \
    if ((kt) < K0) { AS_ = A0; KK_ = (kt); } else { AS_ = A1; KK_ = (kt) - K0; }

    // ---- prologue: stage A0,B1,A1,B0(tile0) [buf0]; A0,B1,A1(tile1) [buf1]
    {
        ASEG(0, As0, kk0);
        gload16(As0 + qA[0][0] + kk0, ldsA + wave * 512);
        gload16(As0 + qA[0][1] + kk0, ldsA + 4096 + wave * 512);
        gload16(Bt + qB[1][0], ldsB + 8192 + wave * 512);
        gload16(Bt + qB[1][1], ldsB + 8192 + 4096 + wave * 512);
        gload16(As0 + qA[1][0] + kk0, ldsA + 8192 + wave * 512);
        gload16(As0 + qA[1][1] + kk0, ldsA + 8192 + 4096 + wave * 512);
        gload16(Bt + qB[0][0], ldsB + wave * 512);
        gload16(Bt + qB[0][1], ldsB + 4096 + wave * 512);
        if (NT > 1) {
            ASEG(64, As1, kk1);
            gload16(As1 + qA[0][0] + kk1, ldsA + 16384 + wave * 512);
            gload16(As1 + qA[0][1] + kk1, ldsA + 16384 + 4096 + wave * 512);
            gload16(Bt + qB[1][0] + 64, ldsB + 16384 + 8192 + wave * 512);
            gload16(Bt + qB[1][1] + 64, ldsB + 16384 + 8192 + 4096 + wave * 512);
            gload16(As1 + qA[1][0] + kk1, ldsA + 16384 + 8192 + wave * 512);
            gload16(As1 + qA[1][1] + kk1, ldsA + 16384 + 8192 + 4096 + wave * 512);
            asm volatile("s_waitcnt vmcnt(6)" ::: "memory");   // tile 0 landed
        } else {
            asm volatile("s_waitcnt vmcnt(0)" ::: "memory");
        }
        __builtin_amdgcn_s_barrier();
    }

    for (int t = 0; t < NT; ++t) {
        const int bufb = (t & 1) << 14;       // cur buffer base (u16)
        const int obufb = bufb ^ 16384;       // other buffer
        const int k0 = t << 6;
        bf16x8 af0[4][2], af1[4][2], bfA[2][2], bfB[2][2];

        // ---- P1: reads A-half0 + B-half0; stage B0(t+1)->other; BAR; Q00
        {
            const u16* ab = &ldsA[bufb + (wm * 8) * 512];
#pragma unroll
            for (int mt2 = 0; mt2 < 4; ++mt2)
#pragma unroll
                for (int ks = 0; ks < 2; ++ks)
                    af0[mt2][ks] = *(const bf16x8*)&ab[(mt2 * 2 + ks) * 512 + aSwz];
            const u16* bb = &ldsB[bufb + (wn * 4) * 512];
#pragma unroll
            for (int nt2 = 0; nt2 < 2; ++nt2)
#pragma unroll
                for (int ks = 0; ks < 2; ++ks)
                    bfA[nt2][ks] = *(const bf16x8*)&bb[(nt2 * 2 + ks) * 512 + aSwz];
        }
        if (t + 1 < NT) {   // other-buf target: safe pre-barrier (disjoint)
            gload16(Bt + qB[0][0] + (k0 + 64), ldsB + obufb + wave * 512);
            gload16(Bt + qB[0][1] + (k0 + 64), ldsB + obufb + 4096 + wave * 512);
        }
        __builtin_amdgcn_s_barrier();
        __builtin_amdgcn_s_setprio(1);
#pragma unroll
        for (int mt2 = 0; mt2 < 4; ++mt2)
#pragma unroll
            for (int nt2 = 0; nt2 < 2; ++nt2)
#pragma unroll
                for (int ks = 0; ks < 2; ++ks)
                    acc[mt2][nt2] = __builtin_amdgcn_mfma_f32_16x16x32_bf16(
                        af0[mt2][ks], bfA[nt2][ks], acc[mt2][nt2], 0, 0, 0);
        __builtin_amdgcn_s_setprio(0);

        // ---- P2: reads B-half1; BAR; stage A0(t+2)->cur; Q01
        {
            const u16* bb = &ldsB[bufb + (16 + wn * 4) * 512];
#pragma unroll
            for (int nt2 = 0; nt2 < 2; ++nt2)
#pragma unroll
                for (int ks = 0; ks < 2; ++ks)
                    bfB[nt2][ks] = *(const bf16x8*)&bb[(nt2 * 2 + ks) * 512 + aSwz];
        }
        __builtin_amdgcn_s_barrier();
        if (t + 2 < NT) {   // A-half0(cur): all waves' af0 reads done (BAR P2)
            ASEG(k0 + 128, As2, kk2);
            gload16(As2 + qA[0][0] + kk2, ldsA + bufb + wave * 512);
            gload16(As2 + qA[0][1] + kk2, ldsA + bufb + 4096 + wave * 512);
        }
        __builtin_amdgcn_s_setprio(1);
#pragma unroll
        for (int mt2 = 0; mt2 < 4; ++mt2)
#pragma unroll
            for (int nt2 = 0; nt2 < 2; ++nt2)
#pragma unroll
                for (int ks = 0; ks < 2; ++ks)
                    acc[mt2][2 + nt2] = __builtin_amdgcn_mfma_f32_16x16x32_bf16(
                        af0[mt2][ks], bfB[nt2][ks], acc[mt2][2 + nt2], 0, 0, 0);
        __builtin_amdgcn_s_setprio(0);

        // ---- P3: reads A-half1; BAR; stage B1(t+2)->cur; Q11
        {
            const u16* ab = &ldsA[bufb + (16 + wm * 8) * 512];
#pragma unroll
            for (int mt2 = 0; mt2 < 4; ++mt2)
#pragma unroll
                for (int ks = 0; ks < 2; ++ks)
                    af1[mt2][ks] = *(const bf16x8*)&ab[(mt2 * 2 + ks) * 512 + aSwz];
        }
        __builtin_amdgcn_s_barrier();
        if (t + 2 < NT) {   // B-half1(cur): all waves' bfB reads done (BAR P3)
            gload16(Bt + qB[1][0] + (k0 + 128), ldsB + bufb + 8192 + wave * 512);
            gload16(Bt + qB[1][1] + (k0 + 128), ldsB + bufb + 8192 + 4096 + wave * 512);
        }
        __builtin_amdgcn_s_setprio(1);
#pragma unroll
        for (int mt2 = 0; mt2 < 4; ++mt2)
#pragma unroll
            for (int nt2 = 0; nt2 < 2; ++nt2)
#pragma unroll
                for (int ks = 0; ks < 2; ++ks)
                    acc[4 + mt2][2 + nt2] = __builtin_amdgcn_mfma_f32_16x16x32_bf16(
                        af1[mt2][ks], bfB[nt2][ks], acc[4 + mt2][2 + nt2], 0, 0, 0);
        __builtin_amdgcn_s_setprio(0);

        // ---- P4: BAR; stage A1(t+2)->cur; Q10 (bfA kept live); vmcnt; BAR
        __builtin_amdgcn_s_barrier();
        if (t + 2 < NT) {   // A-half1(cur): all waves' af1 reads done (BAR P4)
            ASEG(k0 + 128, As3, kk3);
            gload16(As3 + qA[1][0] + kk3, ldsA + bufb + 8192 + wave * 512);
            gload16(As3 + qA[1][1] + kk3, ldsA + bufb + 8192 + 4096 + wave * 512);
        }
        __builtin_amdgcn_s_setprio(1);
#pragma unroll
        for (int mt2 = 0; mt2 < 4; ++mt2)
#pragma unroll
            for (int nt2 = 0; nt2 < 2; ++nt2)
#pragma unroll
                for (int ks = 0; ks < 2; ++ks)
                    acc[4 + mt2][nt2] = __builtin_amdgcn_mfma_f32_16x16x32_bf16(
                        af1[mt2][ks], bfA[nt2][ks], acc[4 + mt2][nt2], 0, 0, 0);
        __builtin_amdgcn_s_setprio(0);
        if (t + 2 < NT) {
            asm volatile("s_waitcnt vmcnt(6)" ::: "memory");   // 3 halves in flight
        } else {
            asm volatile("s_waitcnt vmcnt(0)" ::: "memory");   // tail drain
        }
        __builtin_amdgcn_s_barrier();   // publish all waves' landed stages
    }
#undef ASEG

    // ---- epilogue: lane owns 4 consecutive cols (B-row permutation)
    const int q = lane >> 4;
    const int cbase = n0 + wn * 64 + mrow * 4;
    float bv[4];
#pragma unroll
    for (int tt = 0; tt < 4; ++tt) bv[tt] = loadf(bias, cbase + tt, isf);
#pragma unroll
    for (int mt = 0; mt < 8; ++mt) {
        int row0 = m0 + wm * 128 + mt * 16 + q * 4;
#pragma unroll
        for (int r = 0; r < 4; ++r) {
            uint2 pk;
            pk.x = (u32)f2bf(acc[mt][0][r] + bv[0]) |
                   ((u32)f2bf(acc[mt][1][r] + bv[1]) << 16);
            pk.y = (u32)f2bf(acc[mt][2][r] + bv[2]) |
                   ((u32)f2bf(acc[mt][3][r] + bv[3]) << 16);
            *(uint2*)(Cout + (size_t)(row0 + r) * N + cbase) = pk;
        }
    }
}

// ---------------------------------------------------------------- attn + x_mod
// One wave per row: cos(im,hx) -> fac = 1+sigmoid -> xmod = x*fac.
// hx/x read from converted buffers (fp32 input) or raw buffers (bf16 input).
__global__ __launch_bounds__(256) void attn_xmod(
    const u16* __restrict__ im,
    const u16* __restrict__ hxc, const void* __restrict__ hxr,
    const u16* __restrict__ xc, const void* __restrict__ xr,
    const u32* __restrict__ flagp, u16* __restrict__ xmod) {
    const int isf = (int)*flagp;
    const u16* hx = isf ? hxc : (const u16*)hxr;
    const u16* x = isf ? xc : (const u16*)xr;
    const int lane = threadIdx.x & 63;
    const int row = blockIdx.x * 4 + (threadIdx.x >> 6);
    float dot = 0.f, na = 0.f, nb = 0.f;
#pragma unroll
    for (int j = 0; j < 2; ++j) {
        size_t off = (size_t)row * 1024 + lane * 8 + j * 512;
        float a[8], h[8];
        load8(im, off, 0, a);
        load8(hx, off, 0, h);
#pragma unroll
        for (int e = 0; e < 8; ++e) {
            dot += a[e] * h[e]; na += a[e] * a[e]; nb += h[e] * h[e];
        }
    }
#pragma unroll
    for (int off = 32; off > 0; off >>= 1) {
        dot += __shfl_xor(dot, off, 64);
        na += __shfl_xor(na, off, 64);
        nb += __shfl_xor(nb, off, 64);
    }
    float cs = dot / (fmaxf(sqrtf(na), 1e-6f) * fmaxf(sqrtf(nb), 1e-6f));
    float fac = 1.f + sigm(cs);
#pragma unroll
    for (int j = 0; j < 2; ++j) {
        size_t off = (size_t)row * 1024 + lane * 8 + j * 512;
        float a[8];
        load8(x, off, 0, a);
#pragma unroll
        for (int e = 0; e < 8; ++e) a[e] *= fac;
        *(uint4*)(xmod + off) = pack8(a);
    }
}

// ---------------------------------------------------------------- LN + LSTM + cosine-mod
__global__ __launch_bounds__(256) void ln_lstm(
    const u16* __restrict__ gates, const void* __restrict__ cx,
    const void* __restrict__ gammas, const void* __restrict__ betas,
    const u32* __restrict__ flagp, void* __restrict__ out, int BH) {
    const int isf = (int)*flagp;
    const int lane = threadIdx.x & 63;
    const int row = blockIdx.x * 4 + (threadIdx.x >> 6);
    float v[4][16];
    float s[4] = {0.f, 0.f, 0.f, 0.f}, ss[4] = {0.f, 0.f, 0.f, 0.f};
#pragma unroll
    for (int c = 0; c < 4; ++c) {
#pragma unroll
        for (int j = 0; j < 2; ++j) {
            size_t off = (size_t)row * 4096 + c * 1024 + lane * 8 + j * 512;
            float* vp = &v[c][j * 8];
            load8(gates, off, 0, vp);
#pragma unroll
            for (int e = 0; e < 8; ++e) { s[c] += vp[e]; ss[c] += vp[e] * vp[e]; }
        }
    }
#pragma unroll
    for (int off = 32; off > 0; off >>= 1) {
#pragma unroll
        for (int c = 0; c < 4; ++c) {
            s[c] += __shfl_xor(s[c], off, 64);
            ss[c] += __shfl_xor(ss[c], off, 64);
        }
    }
    float mean[4], rstd[4];
#pragma unroll
    for (int c = 0; c < 4; ++c) {
        mean[c] = s[c] * (1.f / 1024.f);
        float var = ss[c] * (1.f / 1024.f) - mean[c] * mean[c];
        rstd[c] = rsqrtf(fmaxf(var, 0.f) + 1e-5f);
    }
#pragma unroll
    for (int c = 0; c < 4; ++c) {
#pragma unroll
        for (int j = 0; j < 2; ++j) {
            size_t off = (size_t)(c * 1024 + lane * 8 + j * 512);
            float g[8], bb[8];
            load8(gammas, off, isf, g);
            load8(betas, off, isf, bb);
            float* vp = &v[c][j * 8];
#pragma unroll
            for (int e = 0; e < 8; ++e) {
                float y = (vp[e] - mean[c]) * rstd[c] * g[e] + bb[e];
                vp[e] = (c == 2) ? tanhf(y) : sigm(y);
            }
        }
    }
    float hn[16], cn[16];
    float dot = 0.f, nh = 0.f, nc = 0.f;
#pragma unroll
    for (int j = 0; j < 2; ++j) {
        size_t off = (size_t)row * 1024 + lane * 8 + j * 512;
        float cv[8];
        load8(cx, off, isf, cv);
#pragma unroll
        for (int e = 0; e < 8; ++e) {
            int idx = j * 8 + e;
            float c_new = v[1][idx] * cv[e] + v[0][idx] * v[2][idx];
            float h_new = v[3][idx] * tanhf(c_new);
            cn[idx] = c_new; hn[idx] = h_new;
            dot += h_new * c_new; nh += h_new * h_new; nc += c_new * c_new;
        }
    }
#pragma unroll
    for (int off = 32; off > 0; off >>= 1) {
        dot += __shfl_xor(dot, off, 64);
        nh += __shfl_xor(nh, off, 64);
        nc += __shfl_xor(nc, off, 64);
    }
    float cs = dot / (fmaxf(sqrtf(nh), 1e-6f) * fmaxf(sqrtf(nc), 1e-6f));
    float fac = 1.f + sigm((cs + 1.f) * 0.5f);
#pragma unroll
    for (int j = 0; j < 2; ++j) {
        size_t off = (size_t)row * 1024 + lane * 8 + j * 512;
        float ho[8];
#pragma unroll
        for (int e = 0; e < 8; ++e) ho[e] = hn[j * 8 + e] * fac;
        store8(out, off, isf, ho);
        store8(out, (size_t)BH + off, isf, &cn[j * 8]);
    }
}

// ---------------------------------------------------------------- diagnostics
__global__ void diag_k(u32* __restrict__ out, int ws_ok, int sizes_ok) {
    const int lane = threadIdx.x & 63;
    int mrow = lane & 15, quad = lane >> 4;
    bf16x8 af, bfr;
#pragma unroll
    for (int j = 0; j < 8; ++j) {
        int k = quad * 8 + j;
        af[j] = (short)f2bf((float)(((mrow * 7 + k * 3) % 11) - 5));
        bfr[j] = (short)f2bf((float)(((mrow * 5 + k * 2) % 13) - 6));
    }
    f32x4 cacc = (f32x4){0.f, 0.f, 0.f, 0.f};
    cacc = __builtin_amdgcn_mfma_f32_16x16x32_bf16(af, bfr, cacc, 0, 0, 0);
    int bad = 0;
#pragma unroll
    for (int r = 0; r < 4; ++r) {
        int mr = quad * 4 + r;
        float expv = 0.f;
        for (int k = 0; k < 32; ++k)
            expv += (float)(((mr * 7 + k * 3) % 11) - 5) *
                    (float)(((mrow * 5 + k * 2) % 13) - 6);
        if (fabsf(cacc[r] - expv) > 0.5f) bad = 1;
    }
    int mfma_bad = (__ballot(bad) != 0ull) ? 1 : 0;
    if (lane == 0) {
        if (!sizes_ok)     out[0] = __builtin_bit_cast(u32, 65536.f);
        else if (!ws_ok)   out[0] = __builtin_bit_cast(u32, 131072.f);
        else if (mfma_bad) out[0] = __builtin_bit_cast(u32, 32768.f);
    }
}

// ---------------------------------------------------------------- launch
extern "C" void kernel_launch(void* const* d_in, const int* in_sizes, int n_in,
                              void* d_out, int out_size, void* d_ws, size_t ws_size,
                              hipStream_t stream) {
    const void* x   = d_in[0];  // [8192,1024]
    const void* hx  = d_in[1];  // [8192,1024]
    const void* cx  = d_in[2];  // [8192,1024]
    const void* W   = d_in[3];  // [2048,4096]
    const void* b   = d_in[4];  // [4096]
    const void* Wm  = d_in[5];  // [1024,1024]
    const void* bm  = d_in[6];  // [1024]
    const void* gam = d_in[7];  // [4,1024]
    const void* bet = d_in[8];  // [4,1024]

    const int B = 8192, I = 1024, H = 1024;
    const int K2 = I + H, N2 = 4 * H;
    const size_t MiB = 1048576ull;

    // ws layout (bf16 working buffers; 114 MiB + flag):
    //   x_c   [8192,1024] @ 0      (16 MiB)  (fp32-input path only)
    //   hx_c  [8192,1024] @ 16     (16 MiB)  (fp32-input path only)
    //   Wt    [4096,2048] @ 32     (16 MiB)
    //   Wmt   [1024,1024] @ 48     (2 MiB)
    //   gates [8192,4096] @ 50     (64 MiB)
    //   flag  u32         @ 114 MiB
    // d_out as scratch: xmod(bf16) @ 0, imb(bf16) @ 16 MiB (dead before ln_lstm).
    char* ws = (char*)d_ws;
    u16* x_c   = (u16*)ws;
    u16* hx_c  = (u16*)(ws + 16 * MiB);
    u16* Wt    = (u16*)(ws + 32 * MiB);
    u16* Wmt   = (u16*)(ws + 48 * MiB);
    u16* gates = (u16*)(ws + 50 * MiB);
    u32* flag  = (u32*)(ws + 114 * MiB);
    u16* xmod  = (u16*)d_out;
    u16* imb   = (u16*)d_out + 8388608ull;

    const int sizes_ok =
        n_in == 9 && out_size == 16777216 &&
        in_sizes[0] == 8388608 && in_sizes[1] == 8388608 && in_sizes[2] == 8388608 &&
        in_sizes[3] == 8388608 && in_sizes[4] == 4096 && in_sizes[5] == 1048576 &&
        in_sizes[6] == 1024 && in_sizes[7] == 4096 && in_sizes[8] == 4096;
    const int ws_ok = ws_size >= 115 * MiB;

    if (sizes_ok && ws_ok) {
        detect_dtype<<<1, 64, 0, stream>>>((const u32*)x, flag);
        cvt_bf16<<<4096, 256, 0, stream>>>(x, x_c, 1048576, flag);   // no-op if bf16
        cvt_bf16<<<4096, 256, 0, stream>>>(hx, hx_c, 1048576, flag); // no-op if bf16
        tr_any<<<dim3(H / 32, I / 32), 256, 0, stream>>>(Wm, Wmt, I, H, flag);
        tr_any<<<dim3(N2 / 32, K2 / 32), 256, 0, stream>>>(W, Wt, K2, N2, flag);
        // im = x @ Wm + bm   (K == K0 == 1024; A1 unused)
        gemm256<<<dim3(H / 256, B / 256), 512, 0, stream>>>(
            x_c, x, x_c, x, I, Wmt, bm, flag, imb, B, H, I);
        attn_xmod<<<dim3(B / 4), 256, 0, stream>>>(imb, hx_c, hx, x_c, x, flag, xmod);
        // gates = [xmod|hx] @ W + b   (both segments lda == K0 == 1024)
        gemm256<<<dim3(N2 / 256, B / 256), 512, 0, stream>>>(
            xmod, xmod, hx_c, hx, I, Wt, b, flag, gates, B, N2, K2);
        ln_lstm<<<dim3(B / 4), 256, 0, stream>>>(gates, cx, gam, bet, flag,
                                                 d_out, B * H);
    }
    diag_k<<<1, 64, 0, stream>>>((u32*)d_out, ws_ok, sizes_ok);
}

// Round 4
// 411.259 us; speedup vs baseline: 2.2312x; 1.0022x over previous
//
#include <hip/hip_runtime.h>
#include <hip/hip_bf16.h>

#define DEV __device__ __forceinline__

typedef unsigned short u16;
typedef unsigned int u32;
typedef __attribute__((ext_vector_type(8))) short bf16x8;
typedef __attribute__((ext_vector_type(4))) float f32x4;

DEV float bf2f(u16 v) { u32 u = ((u32)v) << 16; return __builtin_bit_cast(float, u); }
DEV u16 f2bf(float f) {
    u32 u = __builtin_bit_cast(u32, f);
    u32 r = (u + 0x7fffu + ((u >> 16) & 1u)) >> 16;
    return (u16)r;
}
DEV float lo16(u32 u) { return __builtin_bit_cast(float, u << 16); }
DEV float hi16(u32 u) { return __builtin_bit_cast(float, u & 0xffff0000u); }
DEV float sigm(float x) { return 1.f / (1.f + __expf(-x)); }
// clamp that also swallows NaN (fmaxf(NaN,a)=a): keeps failure modes finite
DEV float clamp4(float v) { return fminf(fmaxf(v, -1e4f), 1e4f); }
// dtype-branching scalar load (isf: 1=fp32, 0=bf16), clamped
DEV float loadf(const void* p, size_t i, int isf) {
    return isf ? clamp4(((const float*)p)[i]) : clamp4(bf2f(((const u16*)p)[i]));
}
// dtype-branching 8-element load, clamped
DEV void load8(const void* p, size_t off, int isf, float* o) {
    if (isf) {
        const float* s = (const float*)p + off;
#pragma unroll
        for (int e = 0; e < 8; ++e) o[e] = clamp4(s[e]);
    } else {
        uint4 q = *(const uint4*)((const u16*)p + off);
        o[0] = clamp4(lo16(q.x)); o[1] = clamp4(hi16(q.x));
        o[2] = clamp4(lo16(q.y)); o[3] = clamp4(hi16(q.y));
        o[4] = clamp4(lo16(q.z)); o[5] = clamp4(hi16(q.z));
        o[6] = clamp4(lo16(q.w)); o[7] = clamp4(hi16(q.w));
    }
}
DEV uint4 pack8(const float* a) {
    uint4 q;
    q.x = (u32)f2bf(a[0]) | ((u32)f2bf(a[1]) << 16);
    q.y = (u32)f2bf(a[2]) | ((u32)f2bf(a[3]) << 16);
    q.z = (u32)f2bf(a[4]) | ((u32)f2bf(a[5]) << 16);
    q.w = (u32)f2bf(a[6]) | ((u32)f2bf(a[7]) << 16);
    return q;
}
// dtype-branching 8-element store (isf: 1=fp32, 0=bf16 packed)
DEV void store8(void* p, size_t off, int isf, const float* a) {
    if (isf) {
        float* d = (float*)p + off;
        *(float4*)(d) = (float4){a[0], a[1], a[2], a[3]};
        *(float4*)(d + 4) = (float4){a[4], a[5], a[6], a[7]};
    } else {
        *(uint4*)((u16*)p + off) = pack8(a);
    }
}

// async global->LDS, 16B per lane. LDS dest is wave-uniform base + lane*16;
// global src is per-lane. (m97/m201 staging pattern)
DEV void gload16(const void* g, void* l) {
    __builtin_amdgcn_global_load_lds(
        (const __attribute__((address_space(1))) void*)g,
        (__attribute__((address_space(3))) void*)l, 16, 0, 0);
}

// ---------------------------------------------------------------- dtype detect
__global__ void detect_dtype(const u32* __restrict__ xw, u32* __restrict__ flag) {
    const int lane = threadIdx.x & 63;
    int cnt = 0;
    for (int k = 0; k < 32; ++k) {
        u32 e = (xw[lane + 64 * k] >> 7) & 0xff;
        cnt += (e >= 118 && e <= 130) ? 1 : 0;
    }
#pragma unroll
    for (int off = 32; off > 0; off >>= 1) cnt += __shfl_xor(cnt, off, 64);
    if (lane == 0) *flag = (cnt > 1024) ? 0u : 1u;
}

// ---------------------------------------------------------------- convert x+hx to bf16 (fused)
// One dispatch converts both tensors (fp32 path); no-op when input is bf16.
__global__ __launch_bounds__(256) void cvt2_bf16(
    const void* __restrict__ sa, const void* __restrict__ sb,
    u16* __restrict__ da, u16* __restrict__ db, int n8each,
    const u32* __restrict__ flagp) {
    const int isf = (int)*flagp;
    if (!isf) return;
    int i = blockIdx.x * 256 + threadIdx.x;
    const void* s; u16* d; int j;
    if (i < n8each) { s = sa; d = da; j = i; }
    else            { s = sb; d = db; j = i - n8each; }
    size_t off = (size_t)j * 8;
    float a[8];
    load8(s, off, 1, a);
    *(uint4*)(d + off) = pack8(a);
}

// ---------------------------------------------------------------- transpose (+convert+clamp)
__global__ __launch_bounds__(256) void tr_any(const void* __restrict__ src,
                                              u16* __restrict__ dst,
                                              int R, int C,
                                              const u32* __restrict__ flagp) {
    const int isf = (int)*flagp;
    __shared__ __align__(16) u16 t[32][33];
    int tx = threadIdx.x & 31, ty = threadIdx.x >> 5;
    int c0 = blockIdx.x * 32, r0 = blockIdx.y * 32;
#pragma unroll
    for (int i = 0; i < 32; i += 8)
        t[ty + i][tx] = f2bf(loadf(src, (size_t)(r0 + ty + i) * C + (c0 + tx), isf));
    __syncthreads();
#pragma unroll
    for (int i = 0; i < 32; i += 8)
        dst[(size_t)(c0 + ty + i) * R + (r0 + tx)] = t[tx][ty + i];
}

// ---------------------------------------------------------------- GEMM 256x256
// C[M,N] = Acat[M,K] * Bt[N,K]^T + bias. bf16 in, fp32 acc, bf16 out.
// m201 geometry: BM=BN=256, BK=64, 8 waves (2Mx4N), 128KiB LDS (2 dbuf),
// global_load_lds w16, counted vmcnt(6), st_16x32 swizzle as linear-LDS-dest +
// inverse-swizzled global source + swizzled ds_read.
//
// Round-4 schedule: TRUE one-phase read-ahead. Quadrant order
// Q00(af0,bfA) -> Q10(af1,bfA) -> Q01(af0,bfB) -> Q11(af1,bfB): the last
// quadrant's operands (af1,bfB) are disjoint from the next tile's first
// quadrant's (af0,bfA), so the cross-tile pre-read reuses af0/bfA registers
// (no double-buffer, no WAR). Every ds_read is issued >= one MFMA cluster
// before its consumer:
//   af0,bfA(t) read in W3(t-1) after vmcnt-barrier (overlap Q11(t-1))
//   af1(t)    read in W1(t) (overlap prev Q11 tail / pre-BAR)
//   bfB(t)    read in W2(t) pre-BAR (overlap Q00)
// Stage hazards (all re-proved): a stage to slot X is issued after a barrier
// that in every wave follows the consuming-MFMA *issue* of X's last read,
// which implies read completion (compiler lgkmcnt before MFMA). Stage order
// B0(t+1)@W1, A0(t+2)@W2, B1(t+2)@W3, A1(t+2)@W3 => identical vmcnt(6)
// ledger: at W3(t) wait, landed through B0(t+1) = tile t+1 complete, so the
// post-barrier pre-reads of tile t+1 are safe. 4 barriers + 1 vmcnt per tile.
__global__ __launch_bounds__(512, 2) void gemm256(
    const u16* __restrict__ A0c, const void* __restrict__ A0r,
    const u16* __restrict__ A1c, const void* __restrict__ A1r, int K0,
    const u16* __restrict__ Bt, const void* __restrict__ bias,
    const u32* __restrict__ flagp,
    u16* __restrict__ Cout, int M, int N, int K) {
    const int isf = (int)*flagp;
    const u16* const A0 = isf ? A0c : (const u16*)A0r;
    const u16* const A1 = isf ? A1c : (const u16*)A1r;
    __shared__ __align__(16) u16 lds[65536];   // A: [0,32768) u16, B: [32768,65536)
    u16* const ldsA = lds;
    u16* const ldsB = lds + 32768;
    const int tid = threadIdx.x;
    const int wave = tid >> 6, lane = tid & 63;
    const int wm = wave >> 2, wn = wave & 3;

    // XCD-aware chunked swizzle (m192): nwg % 8 == 0 for both launches.
    int bx = blockIdx.x, by = blockIdx.y;
    {
        const int gx = gridDim.x;
        const int nwg = gx * gridDim.y;
        if ((nwg & 7) == 0) {
            int lid = by * gx + bx;
            int swz = (lid & 7) * (nwg >> 3) + (lid >> 3);
            bx = swz % gx; by = swz / gx;
        }
    }
    const int m0 = by * 256, n0 = bx * 256;
    const int NT = K >> 6;

    // ---- per-thread stage-source element offsets (tile-invariant).
    // Stage call (h=half, c=call) writes LDS physical bytes p..p+15; decode
    // which LOGICAL element lands there (inverse of the read swizzle) and
    // point the global source at it. lda == K0 for both A segments.
    size_t qA[2][2], qB[2][2];
#pragma unroll
    for (int h = 0; h < 2; ++h)
#pragma unroll
        for (int c = 0; c < 2; ++c) {
            int p = h * 16384 + c * 8192 + wave * 1024 + lane * 16;
            int lg = p ^ (((p >> 9) & 1) << 5);
            int s = lg >> 10, lr = (lg >> 6) & 15;
            int k = ((s & 1) << 5) + ((lg & 63) >> 1);
            int m = ((s >> 3) & 1) * 128 + ((s >> 4) & 1) * 64 +
                    ((s >> 1) & 3) * 16 + lr;
            qA[h][c] = (size_t)(m0 + m) * (size_t)K0 + (size_t)k;
            int ns = ((s >> 2) & 3) * 64 + ((s >> 4) & 1) * 32 +
                     ((s >> 1) & 1) * 16 + lr;
            int gn = (ns & ~63) | ((ns & 15) * 4 + ((ns >> 4) & 3));
            qB[h][c] = (size_t)(n0 + gn) * (size_t)K + (size_t)k;
        }

    // ds_read fragment addressing (swizzled)
    const int mrow = lane & 15;
    const int kfr = (lane >> 4) * 8;
    const int aSwz = (mrow * 32 + kfr) ^ ((mrow & 8) << 1);

    f32x4 acc[8][4];
#pragma unroll
    for (int i = 0; i < 8; ++i)
#pragma unroll
        for (int j = 0; j < 4; ++j) acc[i][j] = (f32x4){0.f, 0.f, 0.f, 0.f};

#define ASEG(kt, AS_, KK_) const u16* AS_; int KK_; \
    if ((kt) < K0) { AS_ = A0; KK_ = (kt); } else { AS_ = A1; KK_ = (kt) - K0; }

    // ---- prologue: stage A0,B1,A1,B0(tile0) [buf0]; A0,B1,A1(tile1) [buf1]
    {
        ASEG(0, As0, kk0);
        gload16(As0 + qA[0][0] + kk0, ldsA + wave * 512);
        gload16(As0 + qA[0][1] + kk0, ldsA + 4096 + wave * 512);
        gload16(Bt + qB[1][0], ldsB + 8192 + wave * 512);
        gload16(Bt + qB[1][1], ldsB + 8192 + 4096 + wave * 512);
        gload16(As0 + qA[1][0] + kk0, ldsA + 8192 + wave * 512);
        gload16(As0 + qA[1][1] + kk0, ldsA + 8192 + 4096 + wave * 512);
        gload16(Bt + qB[0][0], ldsB + wave * 512);
        gload16(Bt + qB[0][1], ldsB + 4096 + wave * 512);
        if (NT > 1) {
            ASEG(64, As1, kk1);
            gload16(As1 + qA[0][0] + kk1, ldsA + 16384 + wave * 512);
            gload16(As1 + qA[0][1] + kk1, ldsA + 16384 + 4096 + wave * 512);
            gload16(Bt + qB[1][0] + 64, ldsB + 16384 + 8192 + wave * 512);
            gload16(Bt + qB[1][1] + 64, ldsB + 16384 + 8192 + 4096 + wave * 512);
            gload16(As1 + qA[1][0] + kk1, ldsA + 16384 + 8192 + wave * 512);
            gload16(As1 + qA[1][1] + kk1, ldsA + 16384 + 8192 + 4096 + wave * 512);
            asm volatile("s_waitcnt vmcnt(6)" ::: "memory");   // tile 0 landed
        } else {
            asm volatile("s_waitcnt vmcnt(0)" ::: "memory");
        }
        __builtin_amdgcn_s_barrier();
    }

    bf16x8 af0[4][2], af1[4][2], bfA[2][2], bfB[2][2];
    // ---- pre-read tile 0's first-quadrant fragments (A-half0, B-half0, buf0)
    {
        const u16* ab = &ldsA[(wm * 8) * 512];
#pragma unroll
        for (int mt2 = 0; mt2 < 4; ++mt2)
#pragma unroll
            for (int ks = 0; ks < 2; ++ks)
                af0[mt2][ks] = *(const bf16x8*)&ab[(mt2 * 2 + ks) * 512 + aSwz];
        const u16* bb = &ldsB[(wn * 4) * 512];
#pragma unroll
        for (int nt2 = 0; nt2 < 2; ++nt2)
#pragma unroll
            for (int ks = 0; ks < 2; ++ks)
                bfA[nt2][ks] = *(const bf16x8*)&bb[(nt2 * 2 + ks) * 512 + aSwz];
    }

    for (int t = 0; t < NT; ++t) {
        const int bufb = (t & 1) << 14;       // cur buffer base (u16)
        const int obufb = bufb ^ 16384;       // other buffer
        const int k0 = t << 6;

        // ---- W1: read af1(t); stage B0(t+1)->obuf; BAR; Q00(af0,bfA)
        {
            const u16* ab = &ldsA[bufb + (16 + wm * 8) * 512];
#pragma unroll
            for (int mt2 = 0; mt2 < 4; ++mt2)
#pragma unroll
                for (int ks = 0; ks < 2; ++ks)
                    af1[mt2][ks] = *(const bf16x8*)&ab[(mt2 * 2 + ks) * 512 + aSwz];
        }
        if (t + 1 < NT) {   // other-buf target: disjoint from all live reads
            gload16(Bt + qB[0][0] + (k0 + 64), ldsB + obufb + wave * 512);
            gload16(Bt + qB[0][1] + (k0 + 64), ldsB + obufb + 4096 + wave * 512);
        }
        __builtin_amdgcn_s_barrier();
        __builtin_amdgcn_s_setprio(1);
#pragma unroll
        for (int mt2 = 0; mt2 < 4; ++mt2)
#pragma unroll
            for (int nt2 = 0; nt2 < 2; ++nt2)
#pragma unroll
                for (int ks = 0; ks < 2; ++ks)
                    acc[mt2][nt2] = __builtin_amdgcn_mfma_f32_16x16x32_bf16(
                        af0[mt2][ks], bfA[nt2][ks], acc[mt2][nt2], 0, 0, 0);
        __builtin_amdgcn_s_setprio(0);

        // ---- W2: read bfB(t); BAR; stage A0(t+2)->cur; Q10(af1,bfA); Q01(af0,bfB)
        {
            const u16* bb = &ldsB[bufb + (16 + wn * 4) * 512];
#pragma unroll
            for (int nt2 = 0; nt2 < 2; ++nt2)
#pragma unroll
                for (int ks = 0; ks < 2; ++ks)
                    bfB[nt2][ks] = *(const bf16x8*)&bb[(nt2 * 2 + ks) * 512 + aSwz];
        }
        __builtin_amdgcn_s_barrier();
        if (t + 2 < NT) {   // A-half0(cur): af0 reads consumed by Q00 pre-BAR
            ASEG(k0 + 128, As2, kk2);
            gload16(As2 + qA[0][0] + kk2, ldsA + bufb + wave * 512);
            gload16(As2 + qA[0][1] + kk2, ldsA + bufb + 4096 + wave * 512);
        }
        __builtin_amdgcn_s_setprio(1);
#pragma unroll
        for (int mt2 = 0; mt2 < 4; ++mt2)
#pragma unroll
            for (int nt2 = 0; nt2 < 2; ++nt2)
#pragma unroll
                for (int ks = 0; ks < 2; ++ks)
                    acc[4 + mt2][nt2] = __builtin_amdgcn_mfma_f32_16x16x32_bf16(
                        af1[mt2][ks], bfA[nt2][ks], acc[4 + mt2][nt2], 0, 0, 0);
#pragma unroll
        for (int mt2 = 0; mt2 < 4; ++mt2)
#pragma unroll
            for (int nt2 = 0; nt2 < 2; ++nt2)
#pragma unroll
                for (int ks = 0; ks < 2; ++ks)
                    acc[mt2][2 + nt2] = __builtin_amdgcn_mfma_f32_16x16x32_bf16(
                        af0[mt2][ks], bfB[nt2][ks], acc[mt2][2 + nt2], 0, 0, 0);
        __builtin_amdgcn_s_setprio(0);

        // ---- W3: BAR; stage B1,A1(t+2)->cur; vmcnt; BAR; pre-read t+1; Q11(af1,bfB)
        __builtin_amdgcn_s_barrier();
        if (t + 2 < NT) {   // B-half1: bfB consumed by Q01 pre-BAR; A-half1: af1 by Q10
            gload16(Bt + qB[1][0] + (k0 + 128), ldsB + bufb + 8192 + wave * 512);
            gload16(Bt + qB[1][1] + (k0 + 128), ldsB + bufb + 8192 + 4096 + wave * 512);
            ASEG(k0 + 128, As3, kk3);
            gload16(As3 + qA[1][0] + kk3, ldsA + bufb + 8192 + wave * 512);
            gload16(As3 + qA[1][1] + kk3, ldsA + bufb + 8192 + 4096 + wave * 512);
            asm volatile("s_waitcnt vmcnt(6)" ::: "memory");   // t+1 fully landed
        } else {
            asm volatile("s_waitcnt vmcnt(0)" ::: "memory");   // tail drain
        }
        __builtin_amdgcn_s_barrier();   // publish: tile t+1 readable by all waves
        if (t + 1 < NT) {   // pre-read next tile's Q00 fragments (overlap Q11)
            const u16* ab = &ldsA[obufb + (wm * 8) * 512];
#pragma unroll
            for (int mt2 = 0; mt2 < 4; ++mt2)
#pragma unroll
                for (int ks = 0; ks < 2; ++ks)
                    af0[mt2][ks] = *(const bf16x8*)&ab[(mt2 * 2 + ks) * 512 + aSwz];
            const u16* bb = &ldsB[obufb + (wn * 4) * 512];
#pragma unroll
            for (int nt2 = 0; nt2 < 2; ++nt2)
#pragma unroll
                for (int ks = 0; ks < 2; ++ks)
                    bfA[nt2][ks] = *(const bf16x8*)&bb[(nt2 * 2 + ks) * 512 + aSwz];
        }
        __builtin_amdgcn_s_setprio(1);
#pragma unroll
        for (int mt2 = 0; mt2 < 4; ++mt2)
#pragma unroll
            for (int nt2 = 0; nt2 < 2; ++nt2)
#pragma unroll
                for (int ks = 0; ks < 2; ++ks)
                    acc[4 + mt2][2 + nt2] = __builtin_amdgcn_mfma_f32_16x16x32_bf16(
                        af1[mt2][ks], bfB[nt2][ks], acc[4 + mt2][2 + nt2], 0, 0, 0);
        __builtin_amdgcn_s_setprio(0);
    }
#undef ASEG

    // ---- epilogue: lane owns 4 consecutive cols (B-row permutation)
    const int q = lane >> 4;
    const int cbase = n0 + wn * 64 + mrow * 4;
    float bv[4];
#pragma unroll
    for (int tt = 0; tt < 4; ++tt) bv[tt] = loadf(bias, cbase + tt, isf);
#pragma unroll
    for (int mt = 0; mt < 8; ++mt) {
        int row0 = m0 + wm * 128 + mt * 16 + q * 4;
#pragma unroll
        for (int r = 0; r < 4; ++r) {
            uint2 pk;
            pk.x = (u32)f2bf(acc[mt][0][r] + bv[0]) |
                   ((u32)f2bf(acc[mt][1][r] + bv[1]) << 16);
            pk.y = (u32)f2bf(acc[mt][2][r] + bv[2]) |
                   ((u32)f2bf(acc[mt][3][r] + bv[3]) << 16);
            *(uint2*)(Cout + (size_t)(row0 + r) * N + cbase) = pk;
        }
    }
}

// ---------------------------------------------------------------- attn + x_mod
// One wave per row: cos(im,hx) -> fac = 1+sigmoid -> xmod = x*fac.
// hx/x read from converted buffers (fp32 input) or raw buffers (bf16 input).
__global__ __launch_bounds__(256) void attn_xmod(
    const u16* __restrict__ im,
    const u16* __restrict__ hxc, const void* __restrict__ hxr,
    const u16* __restrict__ xc, const void* __restrict__ xr,
    const u32* __restrict__ flagp, u16* __restrict__ xmod) {
    const int isf = (int)*flagp;
    const u16* hx = isf ? hxc : (const u16*)hxr;
    const u16* x = isf ? xc : (const u16*)xr;
    const int lane = threadIdx.x & 63;
    const int row = blockIdx.x * 4 + (threadIdx.x >> 6);
    float dot = 0.f, na = 0.f, nb = 0.f;
#pragma unroll
    for (int j = 0; j < 2; ++j) {
        size_t off = (size_t)row * 1024 + lane * 8 + j * 512;
        float a[8], h[8];
        load8(im, off, 0, a);
        load8(hx, off, 0, h);
#pragma unroll
        for (int e = 0; e < 8; ++e) {
            dot += a[e] * h[e]; na += a[e] * a[e]; nb += h[e] * h[e];
        }
    }
#pragma unroll
    for (int off = 32; off > 0; off >>= 1) {
        dot += __shfl_xor(dot, off, 64);
        na += __shfl_xor(na, off, 64);
        nb += __shfl_xor(nb, off, 64);
    }
    float cs = dot / (fmaxf(sqrtf(na), 1e-6f) * fmaxf(sqrtf(nb), 1e-6f));
    float fac = 1.f + sigm(cs);
#pragma unroll
    for (int j = 0; j < 2; ++j) {
        size_t off = (size_t)row * 1024 + lane * 8 + j * 512;
        float a[8];
        load8(x, off, 0, a);
#pragma unroll
        for (int e = 0; e < 8; ++e) a[e] *= fac;
        *(uint4*)(xmod + off) = pack8(a);
    }
}

// ---------------------------------------------------------------- LN + LSTM + cosine-mod
__global__ __launch_bounds__(256) void ln_lstm(
    const u16* __restrict__ gates, const void* __restrict__ cx,
    const void* __restrict__ gammas, const void* __restrict__ betas,
    const u32* __restrict__ flagp, void* __restrict__ out, int BH) {
    const int isf = (int)*flagp;
    const int lane = threadIdx.x & 63;
    const int row = blockIdx.x * 4 + (threadIdx.x >> 6);
    float v[4][16];
    float s[4] = {0.f, 0.f, 0.f, 0.f}, ss[4] = {0.f, 0.f, 0.f, 0.f};
#pragma unroll
    for (int c = 0; c < 4; ++c) {
#pragma unroll
        for (int j = 0; j < 2; ++j) {
            size_t off = (size_t)row * 4096 + c * 1024 + lane * 8 + j * 512;
            float* vp = &v[c][j * 8];
            load8(gates, off, 0, vp);
#pragma unroll
            for (int e = 0; e < 8; ++e) { s[c] += vp[e]; ss[c] += vp[e] * vp[e]; }
        }
    }
#pragma unroll
    for (int off = 32; off > 0; off >>= 1) {
#pragma unroll
        for (int c = 0; c < 4; ++c) {
            s[c] += __shfl_xor(s[c], off, 64);
            ss[c] += __shfl_xor(ss[c], off, 64);
        }
    }
    float mean[4], rstd[4];
#pragma unroll
    for (int c = 0; c < 4; ++c) {
        mean[c] = s[c] * (1.f / 1024.f);
        float var = ss[c] * (1.f / 1024.f) - mean[c] * mean[c];
        rstd[c] = rsqrtf(fmaxf(var, 0.f) + 1e-5f);
    }
#pragma unroll
    for (int c = 0; c < 4; ++c) {
#pragma unroll
        for (int j = 0; j < 2; ++j) {
            size_t off = (size_t)(c * 1024 + lane * 8 + j * 512);
            float g[8], bb[8];
            load8(gammas, off, isf, g);
            load8(betas, off, isf, bb);
            float* vp = &v[c][j * 8];
#pragma unroll
            for (int e = 0; e < 8; ++e) {
                float y = (vp[e] - mean[c]) * rstd[c] * g[e] + bb[e];
                vp[e] = (c == 2) ? tanhf(y) : sigm(y);
            }
        }
    }
    float hn[16], cn[16];
    float dot = 0.f, nh = 0.f, nc = 0.f;
#pragma unroll
    for (int j = 0; j < 2; ++j) {
        size_t off = (size_t)row * 1024 + lane * 8 + j * 512;
        float cv[8];
        load8(cx, off, isf, cv);
#pragma unroll
        for (int e = 0; e < 8; ++e) {
            int idx = j * 8 + e;
            float c_new = v[1][idx] * cv[e] + v[0][idx] * v[2][idx];
            float h_new = v[3][idx] * tanhf(c_new);
            cn[idx] = c_new; hn[idx] = h_new;
            dot += h_new * c_new; nh += h_new * h_new; nc += c_new * c_new;
        }
    }
#pragma unroll
    for (int off = 32; off > 0; off >>= 1) {
        dot += __shfl_xor(dot, off, 64);
        nh += __shfl_xor(nh, off, 64);
        nc += __shfl_xor(nc, off, 64);
    }
    float cs = dot / (fmaxf(sqrtf(nh), 1e-6f) * fmaxf(sqrtf(nc), 1e-6f));
    float fac = 1.f + sigm((cs + 1.f) * 0.5f);
#pragma unroll
    for (int j = 0; j < 2; ++j) {
        size_t off = (size_t)row * 1024 + lane * 8 + j * 512;
        float ho[8];
#pragma unroll
        for (int e = 0; e < 8; ++e) ho[e] = hn[j * 8 + e] * fac;
        store8(out, off, isf, ho);
        store8(out, (size_t)BH + off, isf, &cn[j * 8]);
    }
}

// ---------------------------------------------------------------- diagnostics
__global__ void diag_k(u32* __restrict__ out, int ws_ok, int sizes_ok) {
    const int lane = threadIdx.x & 63;
    int mrow = lane & 15, quad = lane >> 4;
    bf16x8 af, bfr;
#pragma unroll
    for (int j = 0; j < 8; ++j) {
        int k = quad * 8 + j;
        af[j] = (short)f2bf((float)(((mrow * 7 + k * 3) % 11) - 5));
        bfr[j] = (short)f2bf((float)(((mrow * 5 + k * 2) % 13) - 6));
    }
    f32x4 cacc = (f32x4){0.f, 0.f, 0.f, 0.f};
    cacc = __builtin_amdgcn_mfma_f32_16x16x32_bf16(af, bfr, cacc, 0, 0, 0);
    int bad = 0;
#pragma unroll
    for (int r = 0; r < 4; ++r) {
        int mr = quad * 4 + r;
        float expv = 0.f;
        for (int k = 0; k < 32; ++k)
            expv += (float)(((mr * 7 + k * 3) % 11) - 5) *
                    (float)(((mrow * 5 + k * 2) % 13) - 6);
        if (fabsf(cacc[r] - expv) > 0.5f) bad = 1;
    }
    int mfma_bad = (__ballot(bad) != 0ull) ? 1 : 0;
    if (lane == 0) {
        if (!sizes_ok)     out[0] = __builtin_bit_cast(u32, 65536.f);
        else if (!ws_ok)   out[0] = __builtin_bit_cast(u32, 131072.f);
        else if (mfma_bad) out[0] = __builtin_bit_cast(u32, 32768.f);
    }
}

// ---------------------------------------------------------------- launch
extern "C" void kernel_launch(void* const* d_in, const int* in_sizes, int n_in,
                              void* d_out, int out_size, void* d_ws, size_t ws_size,
                              hipStream_t stream) {
    const void* x   = d_in[0];  // [8192,1024]
    const void* hx  = d_in[1];  // [8192,1024]
    const void* cx  = d_in[2];  // [8192,1024]
    const void* W   = d_in[3];  // [2048,4096]
    const void* b   = d_in[4];  // [4096]
    const void* Wm  = d_in[5];  // [1024,1024]
    const void* bm  = d_in[6];  // [1024]
    const void* gam = d_in[7];  // [4,1024]
    const void* bet = d_in[8];  // [4,1024]

    const int B = 8192, I = 1024, H = 1024;
    const int K2 = I + H, N2 = 4 * H;
    const size_t MiB = 1048576ull;

    // ws layout (bf16 working buffers; 114 MiB + flag):
    //   x_c   [8192,1024] @ 0      (16 MiB)  (fp32-input path only)
    //   hx_c  [8192,1024] @ 16     (16 MiB)  (fp32-input path only)
    //   Wt    [4096,2048] @ 32     (16 MiB)
    //   Wmt   [1024,1024] @ 48     (2 MiB)
    //   gates [8192,4096] @ 50     (64 MiB)
    //   flag  u32         @ 114 MiB
    // d_out as scratch: xmod(bf16) @ 0, imb(bf16) @ 16 MiB (dead before ln_lstm).
    char* ws = (char*)d_ws;
    u16* x_c   = (u16*)ws;
    u16* hx_c  = (u16*)(ws + 16 * MiB);
    u16* Wt    = (u16*)(ws + 32 * MiB);
    u16* Wmt   = (u16*)(ws + 48 * MiB);
    u16* gates = (u16*)(ws + 50 * MiB);
    u32* flag  = (u32*)(ws + 114 * MiB);
    u16* xmod  = (u16*)d_out;
    u16* imb   = (u16*)d_out + 8388608ull;

    const int sizes_ok =
        n_in == 9 && out_size == 16777216 &&
        in_sizes[0] == 8388608 && in_sizes[1] == 8388608 && in_sizes[2] == 8388608 &&
        in_sizes[3] == 8388608 && in_sizes[4] == 4096 && in_sizes[5] == 1048576 &&
        in_sizes[6] == 1024 && in_sizes[7] == 4096 && in_sizes[8] == 4096;
    const int ws_ok = ws_size >= 115 * MiB;

    if (sizes_ok && ws_ok) {
        detect_dtype<<<1, 64, 0, stream>>>((const u32*)x, flag);
        cvt2_bf16<<<8192, 256, 0, stream>>>(x, hx, x_c, hx_c, 1048576, flag);
        tr_any<<<dim3(H / 32, I / 32), 256, 0, stream>>>(Wm, Wmt, I, H, flag);
        tr_any<<<dim3(N2 / 32, K2 / 32), 256, 0, stream>>>(W, Wt, K2, N2, flag);
        // im = x @ Wm + bm   (K == K0 == 1024; A1 unused)
        gemm256<<<dim3(H / 256, B / 256), 512, 0, stream>>>(
            x_c, x, x_c, x, I, Wmt, bm, flag, imb, B, H, I);
        attn_xmod<<<dim3(B / 4), 256, 0, stream>>>(imb, hx_c, hx, x_c, x, flag, xmod);
        // gates = [xmod|hx] @ W + b   (both segments lda == K0 == 1024)
        gemm256<<<dim3(N2 / 256, B / 256), 512, 0, stream>>>(
            xmod, xmod, hx_c, hx, I, Wt, b, flag, gates, B, N2, K2);
        ln_lstm<<<dim3(B / 4), 256, 0, stream>>>(gates, cx, gam, bet, flag,
                                                 d_out, B * H);
    }
    diag_k<<<1, 64, 0, stream>>>((u32*)d_out, ws_ok, sizes_ok);
}